// Round 3
// baseline (475.623 us; speedup 1.0000x reference)
//
#include <hip/hip_runtime.h>
#include <hip/hip_bf16.h>
#include <cstdint>

#define B_ 256
#define T_ 600
#define D_ 256

typedef __attribute__((ext_vector_type(8))) short bf16x8;
typedef __attribute__((ext_vector_type(4))) float f32x4;

__device__ __forceinline__ float fast_sigmoid(float x) {
    return __fdividef(1.0f, 1.0f + __expf(-x));
}
__device__ __forceinline__ float fast_tanh(float x) {
    return 1.0f - __fdividef(2.0f, __expf(2.0f * x) + 1.0f);
}
__device__ __forceinline__ short f2bf(float f) {
    unsigned u = __float_as_uint(f);
    u += 0x7FFF + ((u >> 16) & 1);   // round-to-nearest-even
    return (short)(u >> 16);
}

// ---------------------------------------------------------------------------
// prenet (+ fused init_concat)
// ---------------------------------------------------------------------------
__global__ __launch_bounds__(256) void prenet_kernel(
    const float* __restrict__ pre_in, const float* __restrict__ noise,
    const float* __restrict__ w1, const float* __restrict__ b1,
    const float* __restrict__ w2, const float* __restrict__ b2,
    const float* __restrict__ ctx_in, const float* __restrict__ spk,
    float* __restrict__ Xgru, float* __restrict__ Xrnn)
{
    __shared__ float xin[144];
    __shared__ float p1[256];
    int b = blockIdx.x, t = threadIdx.x;
    float s = spk[b * 256 + t];
    Xgru[b * 640 + t] = ctx_in[b * 256 + t];
    Xgru[b * 640 + 384 + t] = s;
    Xrnn[b * 832 + 512 + t] = s;
    if (t < 64) Xrnn[b * 832 + 768 + t] = noise[b * 64 + t];
    if (t < 80) xin[t] = pre_in[b * 80 + t];
    else if (t < 144) xin[t] = noise[b * 64 + (t - 80)];
    __syncthreads();
    float acc = b1[t];
    const float4* w = (const float4*)(w1 + t * 144);
    const float4* xi = (const float4*)xin;
#pragma unroll 9
    for (int k = 0; k < 36; ++k) {
        float4 wv = w[k]; float4 xv = xi[k];
        acc += wv.x * xv.x + wv.y * xv.y + wv.z * xv.z + wv.w * xv.w;
    }
    p1[t] = fmaxf(acc, 0.f);
    __syncthreads();
    if (t < 128) {
        float a2 = b2[t];
        const float4* w2v = (const float4*)(w2 + t * 256);
        const float4* pv = (const float4*)p1;
#pragma unroll 8
        for (int k = 0; k < 64; ++k) {
            float4 wv = w2v[k]; float4 xv = pv[k];
            a2 += wv.x * xv.x + wv.y * xv.y + wv.z * xv.z + wv.w * xv.w;
        }
        Xgru[b * 640 + 256 + t] = fmaxf(a2, 0.f);
    }
}

// ---------------------------------------------------------------------------
// gemm_dual (unchanged)
// ---------------------------------------------------------------------------
__global__ __launch_bounds__(256) void gemm_dual(
    const float* __restrict__ A1, int K1, const float* __restrict__ B1,
    const float* __restrict__ A2, int K2, const float* __restrict__ B2,
    const float* __restrict__ bias, float* __restrict__ C, int N)
{
    __shared__ float As[16][68];
    __shared__ float Bs[16][68];
    int tid = threadIdx.x;
    int m0 = blockIdx.x * 64, n0 = blockIdx.y * 64;
    int tm = tid & 15, tn = tid >> 4;
    int lm = tid >> 2, lq = tid & 3;
    float acc[4][4] = {};
    int nkt = (K1 + K2) >> 4;
    for (int kt = 0; kt < nkt; ++kt) {
        int kg = kt << 4;
        const float* A; const float* Bb; int kk; int K;
        if (kg < K1) { A = A1; Bb = B1; kk = kg; K = K1; }
        else         { A = A2; Bb = B2; kk = kg - K1; K = K2; }
        float4 av = *(const float4*)&A[(size_t)(m0 + lm) * K + kk + lq * 4];
        float4 bv = *(const float4*)&Bb[(size_t)(n0 + lm) * K + kk + lq * 4];
        __syncthreads();
        As[lq * 4 + 0][lm] = av.x; As[lq * 4 + 1][lm] = av.y;
        As[lq * 4 + 2][lm] = av.z; As[lq * 4 + 3][lm] = av.w;
        Bs[lq * 4 + 0][lm] = bv.x; Bs[lq * 4 + 1][lm] = bv.y;
        Bs[lq * 4 + 2][lm] = bv.z; Bs[lq * 4 + 3][lm] = bv.w;
        __syncthreads();
#pragma unroll
        for (int k = 0; k < 16; ++k) {
            float4 a = *(const float4*)&As[k][tm * 4];
            float4 b = *(const float4*)&Bs[k][tn * 4];
            acc[0][0] = fmaf(a.x, b.x, acc[0][0]);
            acc[0][1] = fmaf(a.x, b.y, acc[0][1]);
            acc[0][2] = fmaf(a.x, b.z, acc[0][2]);
            acc[0][3] = fmaf(a.x, b.w, acc[0][3]);
            acc[1][0] = fmaf(a.y, b.x, acc[1][0]);
            acc[1][1] = fmaf(a.y, b.y, acc[1][1]);
            acc[1][2] = fmaf(a.y, b.z, acc[1][2]);
            acc[1][3] = fmaf(a.y, b.w, acc[1][3]);
            acc[2][0] = fmaf(a.z, b.x, acc[2][0]);
            acc[2][1] = fmaf(a.z, b.y, acc[2][1]);
            acc[2][2] = fmaf(a.z, b.z, acc[2][2]);
            acc[2][3] = fmaf(a.z, b.w, acc[2][3]);
            acc[3][0] = fmaf(a.w, b.x, acc[3][0]);
            acc[3][1] = fmaf(a.w, b.y, acc[3][1]);
            acc[3][2] = fmaf(a.w, b.z, acc[3][2]);
            acc[3][3] = fmaf(a.w, b.w, acc[3][3]);
        }
    }
    float bb[4] = {0.f, 0.f, 0.f, 0.f};
    if (bias) {
        bb[0] = bias[n0 + tn * 4 + 0]; bb[1] = bias[n0 + tn * 4 + 1];
        bb[2] = bias[n0 + tn * 4 + 2]; bb[3] = bias[n0 + tn * 4 + 3];
    }
#pragma unroll
    for (int i = 0; i < 4; ++i) {
        float4 o = make_float4(acc[i][0] + bb[0], acc[i][1] + bb[1],
                               acc[i][2] + bb[2], acc[i][3] + bb[3]);
        *(float4*)&C[(size_t)(m0 + tm * 4 + i) * N + n0 + tn * 4] = o;
    }
}

// ---------------------------------------------------------------------------
// gru_combine
// ---------------------------------------------------------------------------
__global__ __launch_bounds__(256) void gru_combine(
    const float* __restrict__ Cgi, const float* __restrict__ Cgh,
    const float* __restrict__ h_in, float* __restrict__ ah_out,
    float* __restrict__ Xrnn)
{
    int b = blockIdx.x, j = threadIdx.x;
    float gir = Cgi[b * 768 + j], giz = Cgi[b * 768 + 256 + j], gin = Cgi[b * 768 + 512 + j];
    float ghr = Cgh[b * 768 + j], ghz = Cgh[b * 768 + 256 + j], ghn = Cgh[b * 768 + 512 + j];
    float rr = fast_sigmoid(gir + ghr);
    float zz = fast_sigmoid(giz + ghz);
    float nn = fast_tanh(gin + rr * ghn);
    float h = (1.f - zz) * nn + zz * h_in[b * 256 + j];
    ah_out[b * 256 + j] = h;
    Xrnn[b * 832 + 256 + j] = h;
}

// ---------------------------------------------------------------------------
// attn_u v3 (MFMA): pl via mfma_f32_16x16x32_bf16; element pass streams esp.
// grid (10 chunks of 64 t, B), 256 threads (4 waves; wave = one 16-t tile).
// ---------------------------------------------------------------------------
#define TCH 64
__global__ __launch_bounds__(256) void attn_u_kernel(
    const float* __restrict__ esp, const float* __restrict__ pq,
    const float* __restrict__ cum, const float* __restrict__ prv,
    const float* __restrict__ conv_w, const float* __restrict__ L_w,
    const float* __restrict__ L_b, const float* __restrict__ v_w,
    float* __restrict__ u)
{
    __shared__ float loc[TCH][33];
    __shared__ float cw[32 * 62];
    __shared__ float cumL[TCH + 30], prvL[TCH + 30];
    __shared__ float pq2[256], vv[256];
    int b = blockIdx.y;
    int t0 = blockIdx.x * TCH;
    int tid = threadIdx.x;
    for (int i = tid; i < 32 * 62; i += 256) cw[i] = conv_w[i];
    for (int i = tid; i < TCH + 30; i += 256) {
        int tg = t0 + i - 15;
        bool ok = (tg >= 0) && (tg < T_);
        cumL[i] = ok ? cum[b * T_ + tg] : 0.f;
        prvL[i] = ok ? prv[b * T_ + tg] : 0.f;
    }
    pq2[tid] = pq[b * 256 + tid] + L_b[tid];
    vv[tid] = v_w[tid];
    __syncthreads();
    for (int e = tid; e < TCH * 32; e += 256) {
        int t = e >> 5, f = e & 31;
        const float* c0 = &cw[f * 62];
        float acc = 0.f;
#pragma unroll
        for (int k = 0; k < 31; ++k)
            acc += cumL[t + k] * c0[k] + prvL[t + k] * c0[31 + k];
        loc[t][f] = acc;
    }
    __syncthreads();

    int lane = tid & 63, wv = tid >> 6;
    int cl = lane & 15, gr = lane >> 4;

    // A fragment: A[row=t_local][k=f]; lane holds row=lane&15, k=gr*8+j
    bf16x8 afrag;
    {
        int tl = wv * 16 + cl;
#pragma unroll
        for (int j = 0; j < 8; ++j)
            afrag[j] = f2bf(loc[tl][gr * 8 + j]);
    }

    float sums[4] = {0.f, 0.f, 0.f, 0.f};
    const float* espb = esp + (size_t)b * T_ * 256;
    int trow0 = t0 + wv * 16 + gr * 4;
    int tc0 = (trow0 + 0 < T_) ? trow0 + 0 : T_ - 1;
    int tc1 = (trow0 + 1 < T_) ? trow0 + 1 : T_ - 1;
    int tc2 = (trow0 + 2 < T_) ? trow0 + 2 : T_ - 1;
    int tc3 = (trow0 + 3 < T_) ? trow0 + 3 : T_ - 1;
    const float* e0p = espb + (size_t)tc0 * 256 + cl;
    const float* e1p = espb + (size_t)tc1 * 256 + cl;
    const float* e2p = espb + (size_t)tc2 * 256 + cl;
    const float* e3p = espb + (size_t)tc3 * 256 + cl;

#pragma unroll 4
    for (int dt = 0; dt < 16; ++dt) {
        int d = dt * 16 + cl;
        // B fragment: B[k=f][col=d]; lane holds col=lane&15, k=gr*8+j
        const float4* lwp = (const float4*)(L_w + d * 32 + gr * 8);
        float4 w0 = lwp[0], w1 = lwp[1];
        bf16x8 bfrag;
        bfrag[0] = f2bf(w0.x); bfrag[1] = f2bf(w0.y);
        bfrag[2] = f2bf(w0.z); bfrag[3] = f2bf(w0.w);
        bfrag[4] = f2bf(w1.x); bfrag[5] = f2bf(w1.y);
        bfrag[6] = f2bf(w1.z); bfrag[7] = f2bf(w1.w);
        f32x4 acc = {0.f, 0.f, 0.f, 0.f};
        acc = __builtin_amdgcn_mfma_f32_16x16x32_bf16(afrag, bfrag, acc, 0, 0, 0);
        float pqd = pq2[d];
        float vd = vv[d];
        float x0 = e0p[dt * 16] + pqd + acc[0];
        float x1 = e1p[dt * 16] + pqd + acc[1];
        float x2 = e2p[dt * 16] + pqd + acc[2];
        float x3 = e3p[dt * 16] + pqd + acc[3];
        sums[0] = fmaf(fast_tanh(x0), vd, sums[0]);
        sums[1] = fmaf(fast_tanh(x1), vd, sums[1]);
        sums[2] = fmaf(fast_tanh(x2), vd, sums[2]);
        sums[3] = fmaf(fast_tanh(x3), vd, sums[3]);
    }
#pragma unroll
    for (int off = 1; off <= 8; off <<= 1) {
        sums[0] += __shfl_xor(sums[0], off, 64);
        sums[1] += __shfl_xor(sums[1], off, 64);
        sums[2] += __shfl_xor(sums[2], off, 64);
        sums[3] += __shfl_xor(sums[3], off, 64);
    }
    if (cl == 0) {
#pragma unroll
        for (int r = 0; r < 4; ++r) {
            int t = trow0 + r;
            if (t < T_) u[b * T_ + t] = sums[r];
        }
    }
}

// ---------------------------------------------------------------------------
// softmax + context
// ---------------------------------------------------------------------------
__global__ __launch_bounds__(1024) void softmax_ctx_kernel(
    const float* __restrict__ u, const int* __restrict__ plen,
    const float* __restrict__ enc,
    float* __restrict__ scores, float* __restrict__ ctx_out,
    float* __restrict__ Xrnn)
{
    __shared__ float sc[T_];
    __shared__ float red[16];
    __shared__ float part[16][256];
    int b = blockIdx.x, tid = threadIdx.x;
    int lane = tid & 63, wid = tid >> 6;
    int pl = plen[b];
    float mv = -1e30f;
    if (tid < T_) {
        float uv = u[b * T_ + tid];
        mv = (tid < pl) ? uv : -1e9f;
        sc[tid] = mv;
    }
    float m = mv;
#pragma unroll
    for (int off = 32; off > 0; off >>= 1) m = fmaxf(m, __shfl_xor(m, off, 64));
    if (lane == 0) red[wid] = m;
    __syncthreads();
    m = red[0];
#pragma unroll
    for (int i = 1; i < 16; ++i) m = fmaxf(m, red[i]);
    float ev = 0.f;
    if (tid < T_) ev = __expf(sc[tid] - m);
    float s = ev;
    __syncthreads();
#pragma unroll
    for (int off = 32; off > 0; off >>= 1) s += __shfl_xor(s, off, 64);
    if (lane == 0) red[wid] = s;
    __syncthreads();
    float tot = 0.f;
#pragma unroll
    for (int i = 0; i < 16; ++i) tot += red[i];
    float inv = __fdividef(1.0f, tot);
    if (tid < T_) {
        float scv = ev * inv;
        scores[b * T_ + tid] = scv;
        sc[tid] = scv;
    }
    __syncthreads();
    float a0 = 0.f, a1 = 0.f, a2 = 0.f, a3 = 0.f;
    const float4* ep = (const float4*)(enc + ((size_t)b * T_ + wid) * 256) + lane;
    for (int t = wid; t < T_; t += 16) {
        float sv = sc[t];
        float4 ev4 = *ep;
        a0 = fmaf(sv, ev4.x, a0);
        a1 = fmaf(sv, ev4.y, a1);
        a2 = fmaf(sv, ev4.z, a2);
        a3 = fmaf(sv, ev4.w, a3);
        ep += 16 * 64;
    }
    part[wid][lane * 4 + 0] = a0;
    part[wid][lane * 4 + 1] = a1;
    part[wid][lane * 4 + 2] = a2;
    part[wid][lane * 4 + 3] = a3;
    __syncthreads();
    if (tid < 256) {
        float c = 0.f;
#pragma unroll
        for (int q = 0; q < 16; ++q) c += part[q][tid];
        ctx_out[b * 256 + tid] = c;
        Xrnn[b * 832 + tid] = c;
    }
}

// ---------------------------------------------------------------------------
// lstm_combine
// ---------------------------------------------------------------------------
__global__ __launch_bounds__(512) void lstm_combine(
    const float* __restrict__ G, const float* __restrict__ bih,
    const float* __restrict__ bhh, const float* __restrict__ c_in,
    const float* __restrict__ x_in, float* __restrict__ h_out,
    float* __restrict__ c_out, float* __restrict__ x_next)
{
    int b = blockIdx.x, j = threadIdx.x;
    size_t base = (size_t)b * 2048;
    float gi = G[base + j] + bih[j] + bhh[j];
    float gf = G[base + 512 + j] + bih[512 + j] + bhh[512 + j];
    float gg = G[base + 1024 + j] + bih[1024 + j] + bhh[1024 + j];
    float go = G[base + 1536 + j] + bih[1536 + j] + bhh[1536 + j];
    float c = fast_sigmoid(gf) * c_in[b * 512 + j] + fast_sigmoid(gi) * fast_tanh(gg);
    float h = fast_sigmoid(go) * fast_tanh(c);
    h_out[b * 512 + j] = h;
    c_out[b * 512 + j] = c;
    x_next[b * 512 + j] = x_in[b * 512 + j] + h;
}

// ---------------------------------------------------------------------------
// mel
// ---------------------------------------------------------------------------
__global__ __launch_bounds__(256) void mel_kernel(
    const float* __restrict__ x2, const float* __restrict__ mel_w,
    int r, float* __restrict__ mels)
{
    __shared__ float xl[512];
    int b = blockIdx.x, tid = threadIdx.x;
    xl[tid] = x2[b * 512 + tid];
    xl[256 + tid] = x2[b * 512 + 256 + tid];
    __syncthreads();
    for (int idx = tid; idx < 80 * r; idx += 256) {
        int mrow = (idx / r) * 10 + (idx % r);
        const float4* w = (const float4*)(mel_w + (size_t)mrow * 512);
        const float4* xv = (const float4*)xl;
        float acc = 0.f;
#pragma unroll 16
        for (int k = 0; k < 128; ++k) {
            float4 a = w[k], c = xv[k];
            acc += a.x * c.x + a.y * c.y + a.z * c.z + a.w * c.w;
        }
        mels[(size_t)b * 80 * r + idx] = acc;
    }
}

// ---------------------------------------------------------------------------
extern "C" void kernel_launch(void* const* d_in, const int* in_sizes, int n_in,
                              void* d_out, int out_size, void* d_ws, size_t ws_size,
                              hipStream_t stream)
{
    const float* enc    = (const float*)d_in[0];
    const float* esp    = (const float*)d_in[1];
    const float* pre_in = (const float*)d_in[2];
    const float* ah_in  = (const float*)d_in[3];
    const float* h1_in  = (const float*)d_in[4];
    const float* h2_in  = (const float*)d_in[5];
    const float* c1_in  = (const float*)d_in[6];
    const float* c2_in  = (const float*)d_in[7];
    const float* ctx_in = (const float*)d_in[8];
    const float* spk    = (const float*)d_in[9];
    const float* noise  = (const float*)d_in[10];
    const float* cum    = (const float*)d_in[11];
    const float* prv    = (const float*)d_in[12];
    const int*   plen   = (const int*)d_in[13];
    const float* fc1_w  = (const float*)d_in[14];
    const float* fc1_b  = (const float*)d_in[15];
    const float* fc2_w  = (const float*)d_in[16];
    const float* fc2_b  = (const float*)d_in[17];
    const float* conv_w = (const float*)d_in[18];
    const float* L_w    = (const float*)d_in[19];
    const float* L_b    = (const float*)d_in[20];
    const float* W_w    = (const float*)d_in[21];
    const float* W_b    = (const float*)d_in[22];
    const float* v_w    = (const float*)d_in[23];
    const float* g_wih  = (const float*)d_in[24];
    const float* g_whh  = (const float*)d_in[25];
    const float* g_bih  = (const float*)d_in[26];
    const float* g_bhh  = (const float*)d_in[27];
    const float* ri_w   = (const float*)d_in[28];
    const float* ri_b   = (const float*)d_in[29];
    const float* l1_wih = (const float*)d_in[30];
    const float* l1_whh = (const float*)d_in[31];
    const float* l1_bih = (const float*)d_in[32];
    const float* l1_bhh = (const float*)d_in[33];
    const float* l2_wih = (const float*)d_in[34];
    const float* l2_whh = (const float*)d_in[35];
    const float* l2_bih = (const float*)d_in[36];
    const float* l2_bhh = (const float*)d_in[37];
    const float* mel_w  = (const float*)d_in[38];

    int r = (out_size - 808960) / 20480;
    if (r < 1) r = 1;
    if (r > 10) r = 10;

    float* out    = (float*)d_out;
    float* mels   = out;
    float* scores = out + (size_t)20480 * r;
    float* ah_out = scores + 153600;
    float* h1_out = ah_out + 65536;
    float* h2_out = h1_out + 131072;
    float* c1_out = h2_out + 131072;
    float* c2_out = c1_out + 131072;
    float* ctx_out = c2_out + 131072;

    float* ws   = (float*)d_ws;
    float* Xgru = ws;                    // 256*640
    float* Cgi  = Xgru + 163840;         // 256*768
    float* Cgh  = Cgi + 196608;
    float* pq   = Cgh + 196608;          // 256*256
    float* uu   = pq + 65536;            // 256*600
    float* Xrnn = uu + 153600;           // 256*832
    float* x0   = Xrnn + 212992;         // 256*512
    float* x1   = x0 + 131072;
    float* x2   = x1 + 131072;
    float* G    = x2 + 131072;           // 256*2048

    prenet_kernel<<<256, 256, 0, stream>>>(pre_in, noise, fc1_w, fc1_b, fc2_w, fc2_b,
                                           ctx_in, spk, Xgru, Xrnn);
    gemm_dual<<<dim3(4, 12), 256, 0, stream>>>(Xgru, 640, g_wih, nullptr, 0, nullptr, g_bih, Cgi, 768);
    gemm_dual<<<dim3(4, 12), 256, 0, stream>>>(ah_in, 256, g_whh, nullptr, 0, nullptr, g_bhh, Cgh, 768);
    gru_combine<<<256, 256, 0, stream>>>(Cgi, Cgh, ah_in, ah_out, Xrnn);
    gemm_dual<<<dim3(4, 4), 256, 0, stream>>>(ah_out, 256, W_w, nullptr, 0, nullptr, W_b, pq, 256);
    attn_u_kernel<<<dim3(10, 256), 256, 0, stream>>>(esp, pq, cum, prv, conv_w, L_w, L_b, v_w, uu);
    softmax_ctx_kernel<<<256, 1024, 0, stream>>>(uu, plen, enc, scores, ctx_out, Xrnn);
    gemm_dual<<<dim3(4, 8), 256, 0, stream>>>(Xrnn, 832, ri_w, nullptr, 0, nullptr, ri_b, x0, 512);
    gemm_dual<<<dim3(4, 32), 256, 0, stream>>>(x0, 512, l1_wih, h1_in, 512, l1_whh, nullptr, G, 2048);
    lstm_combine<<<256, 512, 0, stream>>>(G, l1_bih, l1_bhh, c1_in, x0, h1_out, c1_out, x1);
    gemm_dual<<<dim3(4, 32), 256, 0, stream>>>(x1, 512, l2_wih, h2_in, 512, l2_whh, nullptr, G, 2048);
    lstm_combine<<<256, 512, 0, stream>>>(G, l2_bih, l2_bhh, c2_in, x1, h2_out, c2_out, x2);
    mel_kernel<<<256, 256, 0, stream>>>(x2, mel_w, r, mels);
}

// Round 4
// 438.992 us; speedup vs baseline: 1.0834x; 1.0834x over previous
//
#include <hip/hip_runtime.h>
#include <hip/hip_bf16.h>
#include <cstdint>

#define B_ 256
#define T_ 600
#define D_ 256

typedef __attribute__((ext_vector_type(8))) short bf16x8;
typedef __attribute__((ext_vector_type(4))) float f32x4;

__device__ __forceinline__ float fast_sigmoid(float x) {
    return __fdividef(1.0f, 1.0f + __expf(-x));
}
__device__ __forceinline__ float fast_tanh(float x) {
    return 1.0f - __fdividef(2.0f, __expf(2.0f * x) + 1.0f);
}
__device__ __forceinline__ short f2bf(float f) {
    unsigned u = __float_as_uint(f);
    u += 0x7FFF + ((u >> 16) & 1);   // round-to-nearest-even
    return (short)(u >> 16);
}

// ---------------------------------------------------------------------------
// prenet (+ fused init_concat)
// ---------------------------------------------------------------------------
__global__ __launch_bounds__(256) void prenet_kernel(
    const float* __restrict__ pre_in, const float* __restrict__ noise,
    const float* __restrict__ w1, const float* __restrict__ b1,
    const float* __restrict__ w2, const float* __restrict__ b2,
    const float* __restrict__ ctx_in, const float* __restrict__ spk,
    float* __restrict__ Xgru, float* __restrict__ Xrnn)
{
    __shared__ float xin[144];
    __shared__ float p1[256];
    int b = blockIdx.x, t = threadIdx.x;
    float s = spk[b * 256 + t];
    Xgru[b * 640 + t] = ctx_in[b * 256 + t];
    Xgru[b * 640 + 384 + t] = s;
    Xrnn[b * 832 + 512 + t] = s;
    if (t < 64) Xrnn[b * 832 + 768 + t] = noise[b * 64 + t];
    if (t < 80) xin[t] = pre_in[b * 80 + t];
    else if (t < 144) xin[t] = noise[b * 64 + (t - 80)];
    __syncthreads();
    float acc = b1[t];
    const float4* w = (const float4*)(w1 + t * 144);
    const float4* xi = (const float4*)xin;
#pragma unroll 9
    for (int k = 0; k < 36; ++k) {
        float4 wv = w[k]; float4 xv = xi[k];
        acc += wv.x * xv.x + wv.y * xv.y + wv.z * xv.z + wv.w * xv.w;
    }
    p1[t] = fmaxf(acc, 0.f);
    __syncthreads();
    if (t < 128) {
        float a2 = b2[t];
        const float4* w2v = (const float4*)(w2 + t * 256);
        const float4* pv = (const float4*)p1;
#pragma unroll 8
        for (int k = 0; k < 64; ++k) {
            float4 wv = w2v[k]; float4 xv = pv[k];
            a2 += wv.x * xv.x + wv.y * xv.y + wv.z * xv.z + wv.w * xv.w;
        }
        Xgru[b * 640 + 256 + t] = fmaxf(a2, 0.f);
    }
}

// ---------------------------------------------------------------------------
// gemm_dual v2: register-prefetch pipeline — load tile kt+1 into regs before
// computing tile kt from LDS, hiding global latency under the FMA block.
// ---------------------------------------------------------------------------
__global__ __launch_bounds__(256) void gemm_dual(
    const float* __restrict__ A1, int K1, const float* __restrict__ B1,
    const float* __restrict__ A2, int K2, const float* __restrict__ B2,
    const float* __restrict__ bias, float* __restrict__ C, int N)
{
    __shared__ float As[16][68];
    __shared__ float Bs[16][68];
    int tid = threadIdx.x;
    int m0 = blockIdx.x * 64, n0 = blockIdx.y * 64;
    int tm = tid & 15, tn = tid >> 4;
    int lm = tid >> 2, lq = tid & 3;
    float acc[4][4] = {};
    int nkt = (K1 + K2) >> 4;

    // prologue: load tile 0
    float4 av, bv;
    {
        const float* A; const float* Bb; int kk; int K;
        if (0 < K1) { A = A1; Bb = B1; kk = 0; K = K1; }
        else        { A = A2; Bb = B2; kk = -K1; K = K2; }
        av = *(const float4*)&A[(size_t)(m0 + lm) * K + kk + lq * 4];
        bv = *(const float4*)&Bb[(size_t)(n0 + lm) * K + kk + lq * 4];
    }
    for (int kt = 0; kt < nkt; ++kt) {
        __syncthreads();
        As[lq * 4 + 0][lm] = av.x; As[lq * 4 + 1][lm] = av.y;
        As[lq * 4 + 2][lm] = av.z; As[lq * 4 + 3][lm] = av.w;
        Bs[lq * 4 + 0][lm] = bv.x; Bs[lq * 4 + 1][lm] = bv.y;
        Bs[lq * 4 + 2][lm] = bv.z; Bs[lq * 4 + 3][lm] = bv.w;
        __syncthreads();
        if (kt + 1 < nkt) {
            int kg = (kt + 1) << 4;
            const float* A; const float* Bb; int kk; int K;
            if (kg < K1) { A = A1; Bb = B1; kk = kg; K = K1; }
            else         { A = A2; Bb = B2; kk = kg - K1; K = K2; }
            av = *(const float4*)&A[(size_t)(m0 + lm) * K + kk + lq * 4];
            bv = *(const float4*)&Bb[(size_t)(n0 + lm) * K + kk + lq * 4];
        }
#pragma unroll
        for (int k = 0; k < 16; ++k) {
            float4 a = *(const float4*)&As[k][tm * 4];
            float4 b = *(const float4*)&Bs[k][tn * 4];
            acc[0][0] = fmaf(a.x, b.x, acc[0][0]);
            acc[0][1] = fmaf(a.x, b.y, acc[0][1]);
            acc[0][2] = fmaf(a.x, b.z, acc[0][2]);
            acc[0][3] = fmaf(a.x, b.w, acc[0][3]);
            acc[1][0] = fmaf(a.y, b.x, acc[1][0]);
            acc[1][1] = fmaf(a.y, b.y, acc[1][1]);
            acc[1][2] = fmaf(a.y, b.z, acc[1][2]);
            acc[1][3] = fmaf(a.y, b.w, acc[1][3]);
            acc[2][0] = fmaf(a.z, b.x, acc[2][0]);
            acc[2][1] = fmaf(a.z, b.y, acc[2][1]);
            acc[2][2] = fmaf(a.z, b.z, acc[2][2]);
            acc[2][3] = fmaf(a.z, b.w, acc[2][3]);
            acc[3][0] = fmaf(a.w, b.x, acc[3][0]);
            acc[3][1] = fmaf(a.w, b.y, acc[3][1]);
            acc[3][2] = fmaf(a.w, b.z, acc[3][2]);
            acc[3][3] = fmaf(a.w, b.w, acc[3][3]);
        }
    }
    float bb[4] = {0.f, 0.f, 0.f, 0.f};
    if (bias) {
        bb[0] = bias[n0 + tn * 4 + 0]; bb[1] = bias[n0 + tn * 4 + 1];
        bb[2] = bias[n0 + tn * 4 + 2]; bb[3] = bias[n0 + tn * 4 + 3];
    }
#pragma unroll
    for (int i = 0; i < 4; ++i) {
        float4 o = make_float4(acc[i][0] + bb[0], acc[i][1] + bb[1],
                               acc[i][2] + bb[2], acc[i][3] + bb[3]);
        *(float4*)&C[(size_t)(m0 + tm * 4 + i) * N + n0 + tn * 4] = o;
    }
}

// ---------------------------------------------------------------------------
// gru_combine
// ---------------------------------------------------------------------------
__global__ __launch_bounds__(256) void gru_combine(
    const float* __restrict__ Cgi, const float* __restrict__ Cgh,
    const float* __restrict__ h_in, float* __restrict__ ah_out,
    float* __restrict__ Xrnn)
{
    int b = blockIdx.x, j = threadIdx.x;
    float gir = Cgi[b * 768 + j], giz = Cgi[b * 768 + 256 + j], gin = Cgi[b * 768 + 512 + j];
    float ghr = Cgh[b * 768 + j], ghz = Cgh[b * 768 + 256 + j], ghn = Cgh[b * 768 + 512 + j];
    float rr = fast_sigmoid(gir + ghr);
    float zz = fast_sigmoid(giz + ghz);
    float nn = fast_tanh(gin + rr * ghn);
    float h = (1.f - zz) * nn + zz * h_in[b * 256 + j];
    ah_out[b * 256 + j] = h;
    Xrnn[b * 832 + 256 + j] = h;
}

// ---------------------------------------------------------------------------
// attn_u v4: all 16 L_w B-fragments preloaded to registers before the loop;
// loop fully unrolled -> no memory-dependent MFMA, esp loads pipelined.
// grid (10 chunks of 64 t, B), 256 threads (4 waves; wave = one 16-t tile).
// ---------------------------------------------------------------------------
#define TCH 64
__global__ __launch_bounds__(256, 4) void attn_u_kernel(
    const float* __restrict__ esp, const float* __restrict__ pq,
    const float* __restrict__ cum, const float* __restrict__ prv,
    const float* __restrict__ conv_w, const float* __restrict__ L_w,
    const float* __restrict__ L_b, const float* __restrict__ v_w,
    float* __restrict__ u)
{
    __shared__ float loc[TCH][33];
    __shared__ float cw[32 * 62];
    __shared__ float cumL[TCH + 30], prvL[TCH + 30];
    __shared__ float pq2[256], vv[256];
    int b = blockIdx.y;
    int t0 = blockIdx.x * TCH;
    int tid = threadIdx.x;
    int lane = tid & 63, wv = tid >> 6;
    int cl = lane & 15, gr = lane >> 4;

    // preload all 16 B-fragments of L_w (independent loads, issued up front)
    bf16x8 bfr[16];
#pragma unroll
    for (int dt = 0; dt < 16; ++dt) {
        int d = dt * 16 + cl;
        const float4* lwp = (const float4*)(L_w + d * 32 + gr * 8);
        float4 w0 = lwp[0], w1 = lwp[1];
        bf16x8 bf;
        bf[0] = f2bf(w0.x); bf[1] = f2bf(w0.y);
        bf[2] = f2bf(w0.z); bf[3] = f2bf(w0.w);
        bf[4] = f2bf(w1.x); bf[5] = f2bf(w1.y);
        bf[6] = f2bf(w1.z); bf[7] = f2bf(w1.w);
        bfr[dt] = bf;
    }

    for (int i = tid; i < 32 * 62; i += 256) cw[i] = conv_w[i];
    for (int i = tid; i < TCH + 30; i += 256) {
        int tg = t0 + i - 15;
        bool ok = (tg >= 0) && (tg < T_);
        cumL[i] = ok ? cum[b * T_ + tg] : 0.f;
        prvL[i] = ok ? prv[b * T_ + tg] : 0.f;
    }
    pq2[tid] = pq[b * 256 + tid] + L_b[tid];
    vv[tid] = v_w[tid];
    __syncthreads();
    for (int e = tid; e < TCH * 32; e += 256) {
        int t = e >> 5, f = e & 31;
        const float* c0 = &cw[f * 62];
        float acc = 0.f;
#pragma unroll
        for (int k = 0; k < 31; ++k)
            acc += cumL[t + k] * c0[k] + prvL[t + k] * c0[31 + k];
        loc[t][f] = acc;
    }
    __syncthreads();

    // A fragment: A[row=t_local][k=f]; lane holds row=lane&15, k=gr*8+j
    bf16x8 afrag;
    {
        int tl = wv * 16 + cl;
#pragma unroll
        for (int j = 0; j < 8; ++j)
            afrag[j] = f2bf(loc[tl][gr * 8 + j]);
    }

    float sums[4] = {0.f, 0.f, 0.f, 0.f};
    const float* espb = esp + (size_t)b * T_ * 256;
    int trow0 = t0 + wv * 16 + gr * 4;
    int tc0 = (trow0 + 0 < T_) ? trow0 + 0 : T_ - 1;
    int tc1 = (trow0 + 1 < T_) ? trow0 + 1 : T_ - 1;
    int tc2 = (trow0 + 2 < T_) ? trow0 + 2 : T_ - 1;
    int tc3 = (trow0 + 3 < T_) ? trow0 + 3 : T_ - 1;
    const float* e0p = espb + (size_t)tc0 * 256 + cl;
    const float* e1p = espb + (size_t)tc1 * 256 + cl;
    const float* e2p = espb + (size_t)tc2 * 256 + cl;
    const float* e3p = espb + (size_t)tc3 * 256 + cl;

#pragma unroll
    for (int dt = 0; dt < 16; ++dt) {
        int d = dt * 16 + cl;
        f32x4 acc = {0.f, 0.f, 0.f, 0.f};
        acc = __builtin_amdgcn_mfma_f32_16x16x32_bf16(afrag, bfr[dt], acc, 0, 0, 0);
        float pqd = pq2[d];
        float vd = vv[d];
        float x0 = e0p[dt * 16] + pqd + acc[0];
        float x1 = e1p[dt * 16] + pqd + acc[1];
        float x2 = e2p[dt * 16] + pqd + acc[2];
        float x3 = e3p[dt * 16] + pqd + acc[3];
        sums[0] = fmaf(fast_tanh(x0), vd, sums[0]);
        sums[1] = fmaf(fast_tanh(x1), vd, sums[1]);
        sums[2] = fmaf(fast_tanh(x2), vd, sums[2]);
        sums[3] = fmaf(fast_tanh(x3), vd, sums[3]);
    }
#pragma unroll
    for (int off = 1; off <= 8; off <<= 1) {
        sums[0] += __shfl_xor(sums[0], off, 64);
        sums[1] += __shfl_xor(sums[1], off, 64);
        sums[2] += __shfl_xor(sums[2], off, 64);
        sums[3] += __shfl_xor(sums[3], off, 64);
    }
    if (cl == 0) {
#pragma unroll
        for (int r = 0; r < 4; ++r) {
            int t = trow0 + r;
            if (t < T_) u[b * T_ + t] = sums[r];
        }
    }
}

// ---------------------------------------------------------------------------
// softmax + context
// ---------------------------------------------------------------------------
__global__ __launch_bounds__(1024) void softmax_ctx_kernel(
    const float* __restrict__ u, const int* __restrict__ plen,
    const float* __restrict__ enc,
    float* __restrict__ scores, float* __restrict__ ctx_out,
    float* __restrict__ Xrnn)
{
    __shared__ float sc[T_];
    __shared__ float red[16];
    __shared__ float part[16][256];
    int b = blockIdx.x, tid = threadIdx.x;
    int lane = tid & 63, wid = tid >> 6;
    int pl = plen[b];
    float mv = -1e30f;
    if (tid < T_) {
        float uv = u[b * T_ + tid];
        mv = (tid < pl) ? uv : -1e9f;
        sc[tid] = mv;
    }
    float m = mv;
#pragma unroll
    for (int off = 32; off > 0; off >>= 1) m = fmaxf(m, __shfl_xor(m, off, 64));
    if (lane == 0) red[wid] = m;
    __syncthreads();
    m = red[0];
#pragma unroll
    for (int i = 1; i < 16; ++i) m = fmaxf(m, red[i]);
    float ev = 0.f;
    if (tid < T_) ev = __expf(sc[tid] - m);
    float s = ev;
    __syncthreads();
#pragma unroll
    for (int off = 32; off > 0; off >>= 1) s += __shfl_xor(s, off, 64);
    if (lane == 0) red[wid] = s;
    __syncthreads();
    float tot = 0.f;
#pragma unroll
    for (int i = 0; i < 16; ++i) tot += red[i];
    float inv = __fdividef(1.0f, tot);
    if (tid < T_) {
        float scv = ev * inv;
        scores[b * T_ + tid] = scv;
        sc[tid] = scv;
    }
    __syncthreads();
    float a0 = 0.f, a1 = 0.f, a2 = 0.f, a3 = 0.f;
    const float4* ep = (const float4*)(enc + ((size_t)b * T_ + wid) * 256) + lane;
    for (int t = wid; t < T_; t += 16) {
        float sv = sc[t];
        float4 ev4 = *ep;
        a0 = fmaf(sv, ev4.x, a0);
        a1 = fmaf(sv, ev4.y, a1);
        a2 = fmaf(sv, ev4.z, a2);
        a3 = fmaf(sv, ev4.w, a3);
        ep += 16 * 64;
    }
    part[wid][lane * 4 + 0] = a0;
    part[wid][lane * 4 + 1] = a1;
    part[wid][lane * 4 + 2] = a2;
    part[wid][lane * 4 + 3] = a3;
    __syncthreads();
    if (tid < 256) {
        float c = 0.f;
#pragma unroll
        for (int q = 0; q < 16; ++q) c += part[q][tid];
        ctx_out[b * 256 + tid] = c;
        Xrnn[b * 832 + tid] = c;
    }
}

// ---------------------------------------------------------------------------
// lstm_combine
// ---------------------------------------------------------------------------
__global__ __launch_bounds__(512) void lstm_combine(
    const float* __restrict__ G, const float* __restrict__ bih,
    const float* __restrict__ bhh, const float* __restrict__ c_in,
    const float* __restrict__ x_in, float* __restrict__ h_out,
    float* __restrict__ c_out, float* __restrict__ x_next)
{
    int b = blockIdx.x, j = threadIdx.x;
    size_t base = (size_t)b * 2048;
    float gi = G[base + j] + bih[j] + bhh[j];
    float gf = G[base + 512 + j] + bih[512 + j] + bhh[512 + j];
    float gg = G[base + 1024 + j] + bih[1024 + j] + bhh[1024 + j];
    float go = G[base + 1536 + j] + bih[1536 + j] + bhh[1536 + j];
    float c = fast_sigmoid(gf) * c_in[b * 512 + j] + fast_sigmoid(gi) * fast_tanh(gg);
    float h = fast_sigmoid(go) * fast_tanh(c);
    h_out[b * 512 + j] = h;
    c_out[b * 512 + j] = c;
    x_next[b * 512 + j] = x_in[b * 512 + j] + h;
}

// ---------------------------------------------------------------------------
// mel
// ---------------------------------------------------------------------------
__global__ __launch_bounds__(256) void mel_kernel(
    const float* __restrict__ x2, const float* __restrict__ mel_w,
    int r, float* __restrict__ mels)
{
    __shared__ float xl[512];
    int b = blockIdx.x, tid = threadIdx.x;
    xl[tid] = x2[b * 512 + tid];
    xl[256 + tid] = x2[b * 512 + 256 + tid];
    __syncthreads();
    for (int idx = tid; idx < 80 * r; idx += 256) {
        int mrow = (idx / r) * 10 + (idx % r);
        const float4* w = (const float4*)(mel_w + (size_t)mrow * 512);
        const float4* xv = (const float4*)xl;
        float acc = 0.f;
#pragma unroll 16
        for (int k = 0; k < 128; ++k) {
            float4 a = w[k], c = xv[k];
            acc += a.x * c.x + a.y * c.y + a.z * c.z + a.w * c.w;
        }
        mels[(size_t)b * 80 * r + idx] = acc;
    }
}

// ---------------------------------------------------------------------------
extern "C" void kernel_launch(void* const* d_in, const int* in_sizes, int n_in,
                              void* d_out, int out_size, void* d_ws, size_t ws_size,
                              hipStream_t stream)
{
    const float* enc    = (const float*)d_in[0];
    const float* esp    = (const float*)d_in[1];
    const float* pre_in = (const float*)d_in[2];
    const float* ah_in  = (const float*)d_in[3];
    const float* h1_in  = (const float*)d_in[4];
    const float* h2_in  = (const float*)d_in[5];
    const float* c1_in  = (const float*)d_in[6];
    const float* c2_in  = (const float*)d_in[7];
    const float* ctx_in = (const float*)d_in[8];
    const float* spk    = (const float*)d_in[9];
    const float* noise  = (const float*)d_in[10];
    const float* cum    = (const float*)d_in[11];
    const float* prv    = (const float*)d_in[12];
    const int*   plen   = (const int*)d_in[13];
    const float* fc1_w  = (const float*)d_in[14];
    const float* fc1_b  = (const float*)d_in[15];
    const float* fc2_w  = (const float*)d_in[16];
    const float* fc2_b  = (const float*)d_in[17];
    const float* conv_w = (const float*)d_in[18];
    const float* L_w    = (const float*)d_in[19];
    const float* L_b    = (const float*)d_in[20];
    const float* W_w    = (const float*)d_in[21];
    const float* W_b    = (const float*)d_in[22];
    const float* v_w    = (const float*)d_in[23];
    const float* g_wih  = (const float*)d_in[24];
    const float* g_whh  = (const float*)d_in[25];
    const float* g_bih  = (const float*)d_in[26];
    const float* g_bhh  = (const float*)d_in[27];
    const float* ri_w   = (const float*)d_in[28];
    const float* ri_b   = (const float*)d_in[29];
    const float* l1_wih = (const float*)d_in[30];
    const float* l1_whh = (const float*)d_in[31];
    const float* l1_bih = (const float*)d_in[32];
    const float* l1_bhh = (const float*)d_in[33];
    const float* l2_wih = (const float*)d_in[34];
    const float* l2_whh = (const float*)d_in[35];
    const float* l2_bih = (const float*)d_in[36];
    const float* l2_bhh = (const float*)d_in[37];
    const float* mel_w  = (const float*)d_in[38];

    int r = (out_size - 808960) / 20480;
    if (r < 1) r = 1;
    if (r > 10) r = 10;

    float* out    = (float*)d_out;
    float* mels   = out;
    float* scores = out + (size_t)20480 * r;
    float* ah_out = scores + 153600;
    float* h1_out = ah_out + 65536;
    float* h2_out = h1_out + 131072;
    float* c1_out = h2_out + 131072;
    float* c2_out = c1_out + 131072;
    float* ctx_out = c2_out + 131072;

    float* ws   = (float*)d_ws;
    float* Xgru = ws;                    // 256*640
    float* Cgi  = Xgru + 163840;         // 256*768
    float* Cgh  = Cgi + 196608;
    float* pq   = Cgh + 196608;          // 256*256
    float* uu   = pq + 65536;            // 256*600
    float* Xrnn = uu + 153600;           // 256*832
    float* x0   = Xrnn + 212992;         // 256*512
    float* x1   = x0 + 131072;
    float* x2   = x1 + 131072;
    float* G    = x2 + 131072;           // 256*2048

    prenet_kernel<<<256, 256, 0, stream>>>(pre_in, noise, fc1_w, fc1_b, fc2_w, fc2_b,
                                           ctx_in, spk, Xgru, Xrnn);
    gemm_dual<<<dim3(4, 12), 256, 0, stream>>>(Xgru, 640, g_wih, nullptr, 0, nullptr, g_bih, Cgi, 768);
    gemm_dual<<<dim3(4, 12), 256, 0, stream>>>(ah_in, 256, g_whh, nullptr, 0, nullptr, g_bhh, Cgh, 768);
    gru_combine<<<256, 256, 0, stream>>>(Cgi, Cgh, ah_in, ah_out, Xrnn);
    gemm_dual<<<dim3(4, 4), 256, 0, stream>>>(ah_out, 256, W_w, nullptr, 0, nullptr, W_b, pq, 256);
    attn_u_kernel<<<dim3(10, 256), 256, 0, stream>>>(esp, pq, cum, prv, conv_w, L_w, L_b, v_w, uu);
    softmax_ctx_kernel<<<256, 1024, 0, stream>>>(uu, plen, enc, scores, ctx_out, Xrnn);
    gemm_dual<<<dim3(4, 8), 256, 0, stream>>>(Xrnn, 832, ri_w, nullptr, 0, nullptr, ri_b, x0, 512);
    gemm_dual<<<dim3(4, 32), 256, 0, stream>>>(x0, 512, l1_wih, h1_in, 512, l1_whh, nullptr, G, 2048);
    lstm_combine<<<256, 512, 0, stream>>>(G, l1_bih, l1_bhh, c1_in, x0, h1_out, c1_out, x1);
    gemm_dual<<<dim3(4, 32), 256, 0, stream>>>(x1, 512, l2_wih, h2_in, 512, l2_whh, nullptr, G, 2048);
    lstm_combine<<<256, 512, 0, stream>>>(G, l2_bih, l2_bhh, c2_in, x1, h2_out, c2_out, x2);
    mel_kernel<<<256, 256, 0, stream>>>(x2, mel_w, r, mels);
}

// Round 5
// 347.540 us; speedup vs baseline: 1.3685x; 1.2631x over previous
//
#include <hip/hip_runtime.h>
#include <hip/hip_bf16.h>
#include <cstdint>

#define B_ 256
#define T_ 600
#define D_ 256

typedef __attribute__((ext_vector_type(8))) short bf16x8;
typedef __attribute__((ext_vector_type(4))) float f32x4;

__device__ __forceinline__ float fast_sigmoid(float x) {
    return __fdividef(1.0f, 1.0f + __expf(-x));
}
__device__ __forceinline__ float fast_tanh(float x) {
    return 1.0f - __fdividef(2.0f, __expf(2.0f * x) + 1.0f);
}
__device__ __forceinline__ short f2bf(float f) {
    unsigned u = __float_as_uint(f);
    u += 0x7FFF + ((u >> 16) & 1);   // round-to-nearest-even
    return (short)(u >> 16);
}

// ---------------------------------------------------------------------------
// prenet (+ fused init_concat)
// ---------------------------------------------------------------------------
__global__ __launch_bounds__(256) void prenet_kernel(
    const float* __restrict__ pre_in, const float* __restrict__ noise,
    const float* __restrict__ w1, const float* __restrict__ b1,
    const float* __restrict__ w2, const float* __restrict__ b2,
    const float* __restrict__ ctx_in, const float* __restrict__ spk,
    float* __restrict__ Xgru, float* __restrict__ Xrnn)
{
    __shared__ float xin[144];
    __shared__ float p1[256];
    int b = blockIdx.x, t = threadIdx.x;
    float s = spk[b * 256 + t];
    Xgru[b * 640 + t] = ctx_in[b * 256 + t];
    Xgru[b * 640 + 384 + t] = s;
    Xrnn[b * 832 + 512 + t] = s;
    if (t < 64) Xrnn[b * 832 + 768 + t] = noise[b * 64 + t];
    if (t < 80) xin[t] = pre_in[b * 80 + t];
    else if (t < 144) xin[t] = noise[b * 64 + (t - 80)];
    __syncthreads();
    float acc = b1[t];
    const float4* w = (const float4*)(w1 + t * 144);
    const float4* xi = (const float4*)xin;
#pragma unroll 9
    for (int k = 0; k < 36; ++k) {
        float4 wv = w[k]; float4 xv = xi[k];
        acc += wv.x * xv.x + wv.y * xv.y + wv.z * xv.z + wv.w * xv.w;
    }
    p1[t] = fmaxf(acc, 0.f);
    __syncthreads();
    if (t < 128) {
        float a2 = b2[t];
        const float4* w2v = (const float4*)(w2 + t * 256);
        const float4* pv = (const float4*)p1;
#pragma unroll 8
        for (int k = 0; k < 64; ++k) {
            float4 wv = w2v[k]; float4 xv = pv[k];
            a2 += wv.x * xv.x + wv.y * xv.y + wv.z * xv.z + wv.w * xv.w;
        }
        Xgru[b * 640 + 256 + t] = fmaxf(a2, 0.f);
    }
}

// ---------------------------------------------------------------------------
// gemm_dual v2: register-prefetch pipeline
// ---------------------------------------------------------------------------
__global__ __launch_bounds__(256) void gemm_dual(
    const float* __restrict__ A1, int K1, const float* __restrict__ B1,
    const float* __restrict__ A2, int K2, const float* __restrict__ B2,
    const float* __restrict__ bias, float* __restrict__ C, int N)
{
    __shared__ float As[16][68];
    __shared__ float Bs[16][68];
    int tid = threadIdx.x;
    int m0 = blockIdx.x * 64, n0 = blockIdx.y * 64;
    int tm = tid & 15, tn = tid >> 4;
    int lm = tid >> 2, lq = tid & 3;
    float acc[4][4] = {};
    int nkt = (K1 + K2) >> 4;

    float4 av, bv;
    {
        const float* A; const float* Bb; int kk; int K;
        if (0 < K1) { A = A1; Bb = B1; kk = 0; K = K1; }
        else        { A = A2; Bb = B2; kk = -K1; K = K2; }
        av = *(const float4*)&A[(size_t)(m0 + lm) * K + kk + lq * 4];
        bv = *(const float4*)&Bb[(size_t)(n0 + lm) * K + kk + lq * 4];
    }
    for (int kt = 0; kt < nkt; ++kt) {
        __syncthreads();
        As[lq * 4 + 0][lm] = av.x; As[lq * 4 + 1][lm] = av.y;
        As[lq * 4 + 2][lm] = av.z; As[lq * 4 + 3][lm] = av.w;
        Bs[lq * 4 + 0][lm] = bv.x; Bs[lq * 4 + 1][lm] = bv.y;
        Bs[lq * 4 + 2][lm] = bv.z; Bs[lq * 4 + 3][lm] = bv.w;
        __syncthreads();
        if (kt + 1 < nkt) {
            int kg = (kt + 1) << 4;
            const float* A; const float* Bb; int kk; int K;
            if (kg < K1) { A = A1; Bb = B1; kk = kg; K = K1; }
            else         { A = A2; Bb = B2; kk = kg - K1; K = K2; }
            av = *(const float4*)&A[(size_t)(m0 + lm) * K + kk + lq * 4];
            bv = *(const float4*)&Bb[(size_t)(n0 + lm) * K + kk + lq * 4];
        }
#pragma unroll
        for (int k = 0; k < 16; ++k) {
            float4 a = *(const float4*)&As[k][tm * 4];
            float4 b = *(const float4*)&Bs[k][tn * 4];
            acc[0][0] = fmaf(a.x, b.x, acc[0][0]);
            acc[0][1] = fmaf(a.x, b.y, acc[0][1]);
            acc[0][2] = fmaf(a.x, b.z, acc[0][2]);
            acc[0][3] = fmaf(a.x, b.w, acc[0][3]);
            acc[1][0] = fmaf(a.y, b.x, acc[1][0]);
            acc[1][1] = fmaf(a.y, b.y, acc[1][1]);
            acc[1][2] = fmaf(a.y, b.z, acc[1][2]);
            acc[1][3] = fmaf(a.y, b.w, acc[1][3]);
            acc[2][0] = fmaf(a.z, b.x, acc[2][0]);
            acc[2][1] = fmaf(a.z, b.y, acc[2][1]);
            acc[2][2] = fmaf(a.z, b.z, acc[2][2]);
            acc[2][3] = fmaf(a.z, b.w, acc[2][3]);
            acc[3][0] = fmaf(a.w, b.x, acc[3][0]);
            acc[3][1] = fmaf(a.w, b.y, acc[3][1]);
            acc[3][2] = fmaf(a.w, b.z, acc[3][2]);
            acc[3][3] = fmaf(a.w, b.w, acc[3][3]);
        }
    }
    float bb[4] = {0.f, 0.f, 0.f, 0.f};
    if (bias) {
        bb[0] = bias[n0 + tn * 4 + 0]; bb[1] = bias[n0 + tn * 4 + 1];
        bb[2] = bias[n0 + tn * 4 + 2]; bb[3] = bias[n0 + tn * 4 + 3];
    }
#pragma unroll
    for (int i = 0; i < 4; ++i) {
        float4 o = make_float4(acc[i][0] + bb[0], acc[i][1] + bb[1],
                               acc[i][2] + bb[2], acc[i][3] + bb[3]);
        *(float4*)&C[(size_t)(m0 + tm * 4 + i) * N + n0 + tn * 4] = o;
    }
}

// ---------------------------------------------------------------------------
// gru_combine
// ---------------------------------------------------------------------------
__global__ __launch_bounds__(256) void gru_combine(
    const float* __restrict__ Cgi, const float* __restrict__ Cgh,
    const float* __restrict__ h_in, float* __restrict__ ah_out,
    float* __restrict__ Xrnn)
{
    int b = blockIdx.x, j = threadIdx.x;
    float gir = Cgi[b * 768 + j], giz = Cgi[b * 768 + 256 + j], gin = Cgi[b * 768 + 512 + j];
    float ghr = Cgh[b * 768 + j], ghz = Cgh[b * 768 + 256 + j], ghn = Cgh[b * 768 + 512 + j];
    float rr = fast_sigmoid(gir + ghr);
    float zz = fast_sigmoid(giz + ghz);
    float nn = fast_tanh(gin + rr * ghn);
    float h = (1.f - zz) * nn + zz * h_in[b * 256 + j];
    ah_out[b * 256 + j] = h;
    Xrnn[b * 832 + 256 + j] = h;
}

// ---------------------------------------------------------------------------
// attn_u v5: v4 structure WITHOUT the VGPR clamp (spills gone).
// Phase A: issue 16 L_w B-frag loads (hide under conv VALU work).
// Phase B: conv -> loc in LDS.
// Phase C: issue all 64 esp loads into registers (independent).
// Phase D: fully-unrolled MFMA + tanh, registers only.
// ---------------------------------------------------------------------------
#define TCH 64
__global__ __launch_bounds__(256) void attn_u_kernel(
    const float* __restrict__ esp, const float* __restrict__ pq,
    const float* __restrict__ cum, const float* __restrict__ prv,
    const float* __restrict__ conv_w, const float* __restrict__ L_w,
    const float* __restrict__ L_b, const float* __restrict__ v_w,
    float* __restrict__ u)
{
    __shared__ float loc[TCH][33];
    __shared__ float cw[32 * 62];
    __shared__ float cumL[TCH + 30], prvL[TCH + 30];
    __shared__ float pq2[256], vv[256];
    int b = blockIdx.y;
    int t0 = blockIdx.x * TCH;
    int tid = threadIdx.x;
    int lane = tid & 63, wv = tid >> 6;
    int cl = lane & 15, gr = lane >> 4;

    // Phase A: preload all 16 B-fragments of L_w (L2-hot after first block)
    bf16x8 bfr[16];
#pragma unroll
    for (int dt = 0; dt < 16; ++dt) {
        int d = dt * 16 + cl;
        const float4* lwp = (const float4*)(L_w + d * 32 + gr * 8);
        float4 w0 = lwp[0], w1 = lwp[1];
        bf16x8 bf;
        bf[0] = f2bf(w0.x); bf[1] = f2bf(w0.y);
        bf[2] = f2bf(w0.z); bf[3] = f2bf(w0.w);
        bf[4] = f2bf(w1.x); bf[5] = f2bf(w1.y);
        bf[6] = f2bf(w1.z); bf[7] = f2bf(w1.w);
        bfr[dt] = bf;
    }

    // Phase B: conv -> loc
    for (int i = tid; i < 32 * 62; i += 256) cw[i] = conv_w[i];
    for (int i = tid; i < TCH + 30; i += 256) {
        int tg = t0 + i - 15;
        bool ok = (tg >= 0) && (tg < T_);
        cumL[i] = ok ? cum[b * T_ + tg] : 0.f;
        prvL[i] = ok ? prv[b * T_ + tg] : 0.f;
    }
    pq2[tid] = pq[b * 256 + tid] + L_b[tid];
    vv[tid] = v_w[tid];
    __syncthreads();
    for (int e = tid; e < TCH * 32; e += 256) {
        int t = e >> 5, f = e & 31;
        const float* c0 = &cw[f * 62];
        float acc = 0.f;
#pragma unroll
        for (int k = 0; k < 31; ++k)
            acc += cumL[t + k] * c0[k] + prvL[t + k] * c0[31 + k];
        loc[t][f] = acc;
    }
    __syncthreads();

    // A fragment: A[row=t_local][k=f]; lane holds row=lane&15, k=gr*8+j
    bf16x8 afrag;
    {
        int tl = wv * 16 + cl;
#pragma unroll
        for (int j = 0; j < 8; ++j)
            afrag[j] = f2bf(loc[tl][gr * 8 + j]);
    }

    const float* espb = esp + (size_t)b * T_ * 256;
    int trow0 = t0 + wv * 16 + gr * 4;
    int tc0 = (trow0 + 0 < T_) ? trow0 + 0 : T_ - 1;
    int tc1 = (trow0 + 1 < T_) ? trow0 + 1 : T_ - 1;
    int tc2 = (trow0 + 2 < T_) ? trow0 + 2 : T_ - 1;
    int tc3 = (trow0 + 3 < T_) ? trow0 + 3 : T_ - 1;
    const float* e0p = espb + (size_t)tc0 * 256 + cl;
    const float* e1p = espb + (size_t)tc1 * 256 + cl;
    const float* e2p = espb + (size_t)tc2 * 256 + cl;
    const float* e3p = espb + (size_t)tc3 * 256 + cl;

    // Phase C: all 64 esp loads issued up front (independent, coalesced)
    float ev[16][4];
#pragma unroll
    for (int dt = 0; dt < 16; ++dt) {
        ev[dt][0] = e0p[dt * 16];
        ev[dt][1] = e1p[dt * 16];
        ev[dt][2] = e2p[dt * 16];
        ev[dt][3] = e3p[dt * 16];
    }

    // Phase D: compute, registers only
    float sums[4] = {0.f, 0.f, 0.f, 0.f};
#pragma unroll
    for (int dt = 0; dt < 16; ++dt) {
        int d = dt * 16 + cl;
        f32x4 acc = {0.f, 0.f, 0.f, 0.f};
        acc = __builtin_amdgcn_mfma_f32_16x16x32_bf16(afrag, bfr[dt], acc, 0, 0, 0);
        float pqd = pq2[d];
        float vd = vv[d];
        float x0 = ev[dt][0] + pqd + acc[0];
        float x1 = ev[dt][1] + pqd + acc[1];
        float x2 = ev[dt][2] + pqd + acc[2];
        float x3 = ev[dt][3] + pqd + acc[3];
        sums[0] = fmaf(fast_tanh(x0), vd, sums[0]);
        sums[1] = fmaf(fast_tanh(x1), vd, sums[1]);
        sums[2] = fmaf(fast_tanh(x2), vd, sums[2]);
        sums[3] = fmaf(fast_tanh(x3), vd, sums[3]);
    }
#pragma unroll
    for (int off = 1; off <= 8; off <<= 1) {
        sums[0] += __shfl_xor(sums[0], off, 64);
        sums[1] += __shfl_xor(sums[1], off, 64);
        sums[2] += __shfl_xor(sums[2], off, 64);
        sums[3] += __shfl_xor(sums[3], off, 64);
    }
    if (cl == 0) {
#pragma unroll
        for (int r = 0; r < 4; ++r) {
            int t = trow0 + r;
            if (t < T_) u[b * T_ + t] = sums[r];
        }
    }
}

// ---------------------------------------------------------------------------
// softmax + context
// ---------------------------------------------------------------------------
__global__ __launch_bounds__(1024) void softmax_ctx_kernel(
    const float* __restrict__ u, const int* __restrict__ plen,
    const float* __restrict__ enc,
    float* __restrict__ scores, float* __restrict__ ctx_out,
    float* __restrict__ Xrnn)
{
    __shared__ float sc[T_];
    __shared__ float red[16];
    __shared__ float part[16][256];
    int b = blockIdx.x, tid = threadIdx.x;
    int lane = tid & 63, wid = tid >> 6;
    int pl = plen[b];
    float mv = -1e30f;
    if (tid < T_) {
        float uv = u[b * T_ + tid];
        mv = (tid < pl) ? uv : -1e9f;
        sc[tid] = mv;
    }
    float m = mv;
#pragma unroll
    for (int off = 32; off > 0; off >>= 1) m = fmaxf(m, __shfl_xor(m, off, 64));
    if (lane == 0) red[wid] = m;
    __syncthreads();
    m = red[0];
#pragma unroll
    for (int i = 1; i < 16; ++i) m = fmaxf(m, red[i]);
    float ev = 0.f;
    if (tid < T_) ev = __expf(sc[tid] - m);
    float s = ev;
    __syncthreads();
#pragma unroll
    for (int off = 32; off > 0; off >>= 1) s += __shfl_xor(s, off, 64);
    if (lane == 0) red[wid] = s;
    __syncthreads();
    float tot = 0.f;
#pragma unroll
    for (int i = 0; i < 16; ++i) tot += red[i];
    float inv = __fdividef(1.0f, tot);
    if (tid < T_) {
        float scv = ev * inv;
        scores[b * T_ + tid] = scv;
        sc[tid] = scv;
    }
    __syncthreads();
    float a0 = 0.f, a1 = 0.f, a2 = 0.f, a3 = 0.f;
    const float4* ep = (const float4*)(enc + ((size_t)b * T_ + wid) * 256) + lane;
    for (int t = wid; t < T_; t += 16) {
        float sv = sc[t];
        float4 ev4 = *ep;
        a0 = fmaf(sv, ev4.x, a0);
        a1 = fmaf(sv, ev4.y, a1);
        a2 = fmaf(sv, ev4.z, a2);
        a3 = fmaf(sv, ev4.w, a3);
        ep += 16 * 64;
    }
    part[wid][lane * 4 + 0] = a0;
    part[wid][lane * 4 + 1] = a1;
    part[wid][lane * 4 + 2] = a2;
    part[wid][lane * 4 + 3] = a3;
    __syncthreads();
    if (tid < 256) {
        float c = 0.f;
#pragma unroll
        for (int q = 0; q < 16; ++q) c += part[q][tid];
        ctx_out[b * 256 + tid] = c;
        Xrnn[b * 832 + tid] = c;
    }
}

// ---------------------------------------------------------------------------
// lstm_combine
// ---------------------------------------------------------------------------
__global__ __launch_bounds__(512) void lstm_combine(
    const float* __restrict__ G, const float* __restrict__ bih,
    const float* __restrict__ bhh, const float* __restrict__ c_in,
    const float* __restrict__ x_in, float* __restrict__ h_out,
    float* __restrict__ c_out, float* __restrict__ x_next)
{
    int b = blockIdx.x, j = threadIdx.x;
    size_t base = (size_t)b * 2048;
    float gi = G[base + j] + bih[j] + bhh[j];
    float gf = G[base + 512 + j] + bih[512 + j] + bhh[512 + j];
    float gg = G[base + 1024 + j] + bih[1024 + j] + bhh[1024 + j];
    float go = G[base + 1536 + j] + bih[1536 + j] + bhh[1536 + j];
    float c = fast_sigmoid(gf) * c_in[b * 512 + j] + fast_sigmoid(gi) * fast_tanh(gg);
    float h = fast_sigmoid(go) * fast_tanh(c);
    h_out[b * 512 + j] = h;
    c_out[b * 512 + j] = c;
    x_next[b * 512 + j] = x_in[b * 512 + j] + h;
}

// ---------------------------------------------------------------------------
// mel
// ---------------------------------------------------------------------------
__global__ __launch_bounds__(256) void mel_kernel(
    const float* __restrict__ x2, const float* __restrict__ mel_w,
    int r, float* __restrict__ mels)
{
    __shared__ float xl[512];
    int b = blockIdx.x, tid = threadIdx.x;
    xl[tid] = x2[b * 512 + tid];
    xl[256 + tid] = x2[b * 512 + 256 + tid];
    __syncthreads();
    for (int idx = tid; idx < 80 * r; idx += 256) {
        int mrow = (idx / r) * 10 + (idx % r);
        const float4* w = (const float4*)(mel_w + (size_t)mrow * 512);
        const float4* xv = (const float4*)xl;
        float acc = 0.f;
#pragma unroll 16
        for (int k = 0; k < 128; ++k) {
            float4 a = w[k], c = xv[k];
            acc += a.x * c.x + a.y * c.y + a.z * c.z + a.w * c.w;
        }
        mels[(size_t)b * 80 * r + idx] = acc;
    }
}

// ---------------------------------------------------------------------------
extern "C" void kernel_launch(void* const* d_in, const int* in_sizes, int n_in,
                              void* d_out, int out_size, void* d_ws, size_t ws_size,
                              hipStream_t stream)
{
    const float* enc    = (const float*)d_in[0];
    const float* esp    = (const float*)d_in[1];
    const float* pre_in = (const float*)d_in[2];
    const float* ah_in  = (const float*)d_in[3];
    const float* h1_in  = (const float*)d_in[4];
    const float* h2_in  = (const float*)d_in[5];
    const float* c1_in  = (const float*)d_in[6];
    const float* c2_in  = (const float*)d_in[7];
    const float* ctx_in = (const float*)d_in[8];
    const float* spk    = (const float*)d_in[9];
    const float* noise  = (const float*)d_in[10];
    const float* cum    = (const float*)d_in[11];
    const float* prv    = (const float*)d_in[12];
    const int*   plen   = (const int*)d_in[13];
    const float* fc1_w  = (const float*)d_in[14];
    const float* fc1_b  = (const float*)d_in[15];
    const float* fc2_w  = (const float*)d_in[16];
    const float* fc2_b  = (const float*)d_in[17];
    const float* conv_w = (const float*)d_in[18];
    const float* L_w    = (const float*)d_in[19];
    const float* L_b    = (const float*)d_in[20];
    const float* W_w    = (const float*)d_in[21];
    const float* W_b    = (const float*)d_in[22];
    const float* v_w    = (const float*)d_in[23];
    const float* g_wih  = (const float*)d_in[24];
    const float* g_whh  = (const float*)d_in[25];
    const float* g_bih  = (const float*)d_in[26];
    const float* g_bhh  = (const float*)d_in[27];
    const float* ri_w   = (const float*)d_in[28];
    const float* ri_b   = (const float*)d_in[29];
    const float* l1_wih = (const float*)d_in[30];
    const float* l1_whh = (const float*)d_in[31];
    const float* l1_bih = (const float*)d_in[32];
    const float* l1_bhh = (const float*)d_in[33];
    const float* l2_wih = (const float*)d_in[34];
    const float* l2_whh = (const float*)d_in[35];
    const float* l2_bih = (const float*)d_in[36];
    const float* l2_bhh = (const float*)d_in[37];
    const float* mel_w  = (const float*)d_in[38];

    int r = (out_size - 808960) / 20480;
    if (r < 1) r = 1;
    if (r > 10) r = 10;

    float* out    = (float*)d_out;
    float* mels   = out;
    float* scores = out + (size_t)20480 * r;
    float* ah_out = scores + 153600;
    float* h1_out = ah_out + 65536;
    float* h2_out = h1_out + 131072;
    float* c1_out = h2_out + 131072;
    float* c2_out = c1_out + 131072;
    float* ctx_out = c2_out + 131072;

    float* ws   = (float*)d_ws;
    float* Xgru = ws;                    // 256*640
    float* Cgi  = Xgru + 163840;         // 256*768
    float* Cgh  = Cgi + 196608;
    float* pq   = Cgh + 196608;          // 256*256
    float* uu   = pq + 65536;            // 256*600
    float* Xrnn = uu + 153600;           // 256*832
    float* x0   = Xrnn + 212992;         // 256*512
    float* x1   = x0 + 131072;
    float* x2   = x1 + 131072;
    float* G    = x2 + 131072;           // 256*2048

    prenet_kernel<<<256, 256, 0, stream>>>(pre_in, noise, fc1_w, fc1_b, fc2_w, fc2_b,
                                           ctx_in, spk, Xgru, Xrnn);
    gemm_dual<<<dim3(4, 12), 256, 0, stream>>>(Xgru, 640, g_wih, nullptr, 0, nullptr, g_bih, Cgi, 768);
    gemm_dual<<<dim3(4, 12), 256, 0, stream>>>(ah_in, 256, g_whh, nullptr, 0, nullptr, g_bhh, Cgh, 768);
    gru_combine<<<256, 256, 0, stream>>>(Cgi, Cgh, ah_in, ah_out, Xrnn);
    gemm_dual<<<dim3(4, 4), 256, 0, stream>>>(ah_out, 256, W_w, nullptr, 0, nullptr, W_b, pq, 256);
    attn_u_kernel<<<dim3(10, 256), 256, 0, stream>>>(esp, pq, cum, prv, conv_w, L_w, L_b, v_w, uu);
    softmax_ctx_kernel<<<256, 1024, 0, stream>>>(uu, plen, enc, scores, ctx_out, Xrnn);
    gemm_dual<<<dim3(4, 8), 256, 0, stream>>>(Xrnn, 832, ri_w, nullptr, 0, nullptr, ri_b, x0, 512);
    gemm_dual<<<dim3(4, 32), 256, 0, stream>>>(x0, 512, l1_wih, h1_in, 512, l1_whh, nullptr, G, 2048);
    lstm_combine<<<256, 512, 0, stream>>>(G, l1_bih, l1_bhh, c1_in, x0, h1_out, c1_out, x1);
    gemm_dual<<<dim3(4, 32), 256, 0, stream>>>(x1, 512, l2_wih, h2_in, 512, l2_whh, nullptr, G, 2048);
    lstm_combine<<<256, 512, 0, stream>>>(G, l2_bih, l2_bhh, c2_in, x1, h2_out, c2_out, x2);
    mel_kernel<<<256, 256, 0, stream>>>(x2, mel_w, r, mels);
}

// Round 6
// 299.158 us; speedup vs baseline: 1.5899x; 1.1617x over previous
//
#include <hip/hip_runtime.h>
#include <hip/hip_bf16.h>
#include <cstdint>

#define B_ 256
#define T_ 600
#define D_ 256

typedef __attribute__((ext_vector_type(8))) short bf16x8;
typedef __attribute__((ext_vector_type(4))) float f32x4;

__device__ __forceinline__ float fast_sigmoid(float x) {
    return __fdividef(1.0f, 1.0f + __expf(-x));
}
__device__ __forceinline__ float fast_tanh(float x) {
    return 1.0f - __fdividef(2.0f, __expf(2.0f * x) + 1.0f);
}
__device__ __forceinline__ ushort f2bf(float f) {
    unsigned u = __float_as_uint(f);
    u += 0x7FFF + ((u >> 16) & 1);   // round-to-nearest-even
    return (ushort)(u >> 16);
}

// ---------------------------------------------------------------------------
// prenet (+ fused init_concat + Lw16 bf16 pre-pack by block 0)
// ---------------------------------------------------------------------------
__global__ __launch_bounds__(256) void prenet_kernel(
    const float* __restrict__ pre_in, const float* __restrict__ noise,
    const float* __restrict__ w1, const float* __restrict__ b1,
    const float* __restrict__ w2, const float* __restrict__ b2,
    const float* __restrict__ ctx_in, const float* __restrict__ spk,
    const float* __restrict__ L_w, ushort* __restrict__ Lw16,
    float* __restrict__ Xgru, float* __restrict__ Xrnn)
{
    __shared__ float xin[144];
    __shared__ float p1[256];
    int b = blockIdx.x, t = threadIdx.x;
    if (b == 0) {
#pragma unroll
        for (int i = 0; i < 32; ++i) {
            int idx = i * 256 + t;
            Lw16[idx] = f2bf(L_w[idx]);
        }
    }
    float s = spk[b * 256 + t];
    Xgru[b * 640 + t] = ctx_in[b * 256 + t];
    Xgru[b * 640 + 384 + t] = s;
    Xrnn[b * 832 + 512 + t] = s;
    if (t < 64) Xrnn[b * 832 + 768 + t] = noise[b * 64 + t];
    if (t < 80) xin[t] = pre_in[b * 80 + t];
    else if (t < 144) xin[t] = noise[b * 64 + (t - 80)];
    __syncthreads();
    float acc = b1[t];
    const float4* w = (const float4*)(w1 + t * 144);
    const float4* xi = (const float4*)xin;
#pragma unroll 9
    for (int k = 0; k < 36; ++k) {
        float4 wv = w[k]; float4 xv = xi[k];
        acc += wv.x * xv.x + wv.y * xv.y + wv.z * xv.z + wv.w * xv.w;
    }
    p1[t] = fmaxf(acc, 0.f);
    __syncthreads();
    if (t < 128) {
        float a2 = b2[t];
        const float4* w2v = (const float4*)(w2 + t * 256);
        const float4* pv = (const float4*)p1;
#pragma unroll 8
        for (int k = 0; k < 64; ++k) {
            float4 wv = w2v[k]; float4 xv = pv[k];
            a2 += wv.x * xv.x + wv.y * xv.y + wv.z * xv.z + wv.w * xv.w;
        }
        Xgru[b * 640 + 256 + t] = fmaxf(a2, 0.f);
    }
}

// ---------------------------------------------------------------------------
// gemm_dual v2: register-prefetch pipeline (unchanged from r5)
// ---------------------------------------------------------------------------
__global__ __launch_bounds__(256) void gemm_dual(
    const float* __restrict__ A1, int K1, const float* __restrict__ B1,
    const float* __restrict__ A2, int K2, const float* __restrict__ B2,
    const float* __restrict__ bias, float* __restrict__ C, int N)
{
    __shared__ float As[16][68];
    __shared__ float Bs[16][68];
    int tid = threadIdx.x;
    int m0 = blockIdx.x * 64, n0 = blockIdx.y * 64;
    int tm = tid & 15, tn = tid >> 4;
    int lm = tid >> 2, lq = tid & 3;
    float acc[4][4] = {};
    int nkt = (K1 + K2) >> 4;

    float4 av, bv;
    {
        const float* A; const float* Bb; int kk; int K;
        if (0 < K1) { A = A1; Bb = B1; kk = 0; K = K1; }
        else        { A = A2; Bb = B2; kk = -K1; K = K2; }
        av = *(const float4*)&A[(size_t)(m0 + lm) * K + kk + lq * 4];
        bv = *(const float4*)&Bb[(size_t)(n0 + lm) * K + kk + lq * 4];
    }
    for (int kt = 0; kt < nkt; ++kt) {
        __syncthreads();
        As[lq * 4 + 0][lm] = av.x; As[lq * 4 + 1][lm] = av.y;
        As[lq * 4 + 2][lm] = av.z; As[lq * 4 + 3][lm] = av.w;
        Bs[lq * 4 + 0][lm] = bv.x; Bs[lq * 4 + 1][lm] = bv.y;
        Bs[lq * 4 + 2][lm] = bv.z; Bs[lq * 4 + 3][lm] = bv.w;
        __syncthreads();
        if (kt + 1 < nkt) {
            int kg = (kt + 1) << 4;
            const float* A; const float* Bb; int kk; int K;
            if (kg < K1) { A = A1; Bb = B1; kk = kg; K = K1; }
            else         { A = A2; Bb = B2; kk = kg - K1; K = K2; }
            av = *(const float4*)&A[(size_t)(m0 + lm) * K + kk + lq * 4];
            bv = *(const float4*)&Bb[(size_t)(n0 + lm) * K + kk + lq * 4];
        }
#pragma unroll
        for (int k = 0; k < 16; ++k) {
            float4 a = *(const float4*)&As[k][tm * 4];
            float4 b = *(const float4*)&Bs[k][tn * 4];
            acc[0][0] = fmaf(a.x, b.x, acc[0][0]);
            acc[0][1] = fmaf(a.x, b.y, acc[0][1]);
            acc[0][2] = fmaf(a.x, b.z, acc[0][2]);
            acc[0][3] = fmaf(a.x, b.w, acc[0][3]);
            acc[1][0] = fmaf(a.y, b.x, acc[1][0]);
            acc[1][1] = fmaf(a.y, b.y, acc[1][1]);
            acc[1][2] = fmaf(a.y, b.z, acc[1][2]);
            acc[1][3] = fmaf(a.y, b.w, acc[1][3]);
            acc[2][0] = fmaf(a.z, b.x, acc[2][0]);
            acc[2][1] = fmaf(a.z, b.y, acc[2][1]);
            acc[2][2] = fmaf(a.z, b.z, acc[2][2]);
            acc[2][3] = fmaf(a.z, b.w, acc[2][3]);
            acc[3][0] = fmaf(a.w, b.x, acc[3][0]);
            acc[3][1] = fmaf(a.w, b.y, acc[3][1]);
            acc[3][2] = fmaf(a.w, b.z, acc[3][2]);
            acc[3][3] = fmaf(a.w, b.w, acc[3][3]);
        }
    }
    float bb[4] = {0.f, 0.f, 0.f, 0.f};
    if (bias) {
        bb[0] = bias[n0 + tn * 4 + 0]; bb[1] = bias[n0 + tn * 4 + 1];
        bb[2] = bias[n0 + tn * 4 + 2]; bb[3] = bias[n0 + tn * 4 + 3];
    }
#pragma unroll
    for (int i = 0; i < 4; ++i) {
        float4 o = make_float4(acc[i][0] + bb[0], acc[i][1] + bb[1],
                               acc[i][2] + bb[2], acc[i][3] + bb[3]);
        *(float4*)&C[(size_t)(m0 + tm * 4 + i) * N + n0 + tn * 4] = o;
    }
}

// ---------------------------------------------------------------------------
// gru_combine
// ---------------------------------------------------------------------------
__global__ __launch_bounds__(256) void gru_combine(
    const float* __restrict__ Cgi, const float* __restrict__ Cgh,
    const float* __restrict__ h_in, float* __restrict__ ah_out,
    float* __restrict__ Xrnn)
{
    int b = blockIdx.x, j = threadIdx.x;
    float gir = Cgi[b * 768 + j], giz = Cgi[b * 768 + 256 + j], gin = Cgi[b * 768 + 512 + j];
    float ghr = Cgh[b * 768 + j], ghz = Cgh[b * 768 + 256 + j], ghn = Cgh[b * 768 + 512 + j];
    float rr = fast_sigmoid(gir + ghr);
    float zz = fast_sigmoid(giz + ghz);
    float nn = fast_tanh(gin + rr * ghn);
    float h = (1.f - zz) * nn + zz * h_in[b * 256 + j];
    ah_out[b * 256 + j] = h;
    Xrnn[b * 832 + 256 + j] = h;
}

// ---------------------------------------------------------------------------
// attn_u v6: swapped-operand MFMA (C[d][t]) -> float4 esp loads.
//  Phase 1: stage cum/prv window + conv_w + pq/v to LDS.
//  Phase 2: conv via register stencil (8 t/thread), loc -> LDS as bf16.
//  Phase 3: afr = 16 pre-packed L_w b128 loads (A-frag, rows=d).
//  Phase 4: per dt: float4 esp + MFMA(C-init=pq) + tanh + fma; 2-shfl reduce.
// grid (10 chunks of 64 t, B), 256 threads = 4 waves x 16 t.
// ---------------------------------------------------------------------------
#define TCH 64
__global__ __launch_bounds__(256) void attn_u_kernel(
    const float* __restrict__ esp, const float* __restrict__ pq,
    const float* __restrict__ cum, const float* __restrict__ prv,
    const float* __restrict__ conv_w, const ushort* __restrict__ Lw16,
    const float* __restrict__ L_b, const float* __restrict__ v_w,
    float* __restrict__ u)
{
    __shared__ float cumL[TCH + 32], prvL[TCH + 32];   // [0] == t0-15
    __shared__ float cwL[32 * 62];
    __shared__ ushort locs[TCH][32];                    // bf16 loc
    __shared__ float pq2s[256], vvs[256];
    int b = blockIdx.y;
    int t0 = blockIdx.x * TCH;
    int tid = threadIdx.x;

    // Phase 1: staging (coalesced)
    for (int i = tid; i < TCH + 30; i += 256) {
        int tg = t0 + i - 15;
        bool ok = (tg >= 0) && (tg < T_);
        cumL[i] = ok ? cum[b * T_ + tg] : 0.f;
        prvL[i] = ok ? prv[b * T_ + tg] : 0.f;
    }
    for (int i = tid; i < 32 * 62; i += 256) cwL[i] = conv_w[i];
    pq2s[tid] = pq[b * 256 + tid] + L_b[tid];
    vvs[tid] = v_w[tid];
    __syncthreads();

    // Phase 2: conv, register stencil. thread = (f = tid&31, ts = tid>>5)
    {
        int f = tid & 31, ts = tid >> 5;
        float wc[31], wp[31];
#pragma unroll
        for (int k = 0; k < 31; ++k) {
            wc[k] = cwL[f * 62 + k];
            wp[k] = cwL[f * 62 + 31 + k];
        }
        float winc[38], winp[38];
#pragma unroll
        for (int k = 0; k < 38; ++k) {
            winc[k] = cumL[ts * 8 + k];   // broadcast reads (32 lanes same addr)
            winp[k] = prvL[ts * 8 + k];
        }
        float acc[8] = {};
#pragma unroll
        for (int i = 0; i < 8; ++i)
#pragma unroll
            for (int k = 0; k < 31; ++k)
                acc[i] = fmaf(winc[i + k], wc[k], fmaf(winp[i + k], wp[k], acc[i]));
#pragma unroll
        for (int i = 0; i < 8; ++i)
            locs[ts * 8 + i][f] = f2bf(acc[i]);
    }

    // Phase 3: A-fragments of L_w (pre-packed bf16). lane: row d=dt*16+cl, k=gr*8+j
    int lane = tid & 63, wv = tid >> 6;
    int cl = lane & 15, gr = lane >> 4;
    bf16x8 afr[16];
#pragma unroll
    for (int dt = 0; dt < 16; ++dt)
        afr[dt] = *(const bf16x8*)&Lw16[(dt * 16 + cl) * 32 + gr * 8];
    __syncthreads();

    // Phase 4: B-frag (col=t) from LDS, then stream esp as float4
    int tw = t0 + wv * 16 + cl;
    int tc = (tw < T_) ? tw : (T_ - 1);
    bf16x8 locf = *(const bf16x8*)&locs[wv * 16 + cl][gr * 8];
    const float4* ep4 = (const float4*)(esp + ((size_t)b * T_ + tc) * 256) + gr;

    float sum = 0.f;
#pragma unroll
    for (int dt = 0; dt < 16; ++dt) {
        float4 pq4 = *(const float4*)&pq2s[dt * 16 + gr * 4];
        float4 vv4 = *(const float4*)&vvs[dt * 16 + gr * 4];
        float4 e4 = ep4[dt * 4];
        f32x4 acc = {pq4.x, pq4.y, pq4.z, pq4.w};
        acc = __builtin_amdgcn_mfma_f32_16x16x32_bf16(afr[dt], locf, acc, 0, 0, 0);
        sum = fmaf(fast_tanh(e4.x + acc[0]), vv4.x, sum);
        sum = fmaf(fast_tanh(e4.y + acc[1]), vv4.y, sum);
        sum = fmaf(fast_tanh(e4.z + acc[2]), vv4.z, sum);
        sum = fmaf(fast_tanh(e4.w + acc[3]), vv4.w, sum);
    }
    sum += __shfl_xor(sum, 16, 64);
    sum += __shfl_xor(sum, 32, 64);
    if (lane < 16 && tw < T_) u[b * T_ + tw] = sum;
}

// ---------------------------------------------------------------------------
// softmax + context
// ---------------------------------------------------------------------------
__global__ __launch_bounds__(1024) void softmax_ctx_kernel(
    const float* __restrict__ u, const int* __restrict__ plen,
    const float* __restrict__ enc,
    float* __restrict__ scores, float* __restrict__ ctx_out,
    float* __restrict__ Xrnn)
{
    __shared__ float sc[T_];
    __shared__ float red[16];
    __shared__ float part[16][256];
    int b = blockIdx.x, tid = threadIdx.x;
    int lane = tid & 63, wid = tid >> 6;
    int pl = plen[b];
    float mv = -1e30f;
    if (tid < T_) {
        float uv = u[b * T_ + tid];
        mv = (tid < pl) ? uv : -1e9f;
        sc[tid] = mv;
    }
    float m = mv;
#pragma unroll
    for (int off = 32; off > 0; off >>= 1) m = fmaxf(m, __shfl_xor(m, off, 64));
    if (lane == 0) red[wid] = m;
    __syncthreads();
    m = red[0];
#pragma unroll
    for (int i = 1; i < 16; ++i) m = fmaxf(m, red[i]);
    float ev = 0.f;
    if (tid < T_) ev = __expf(sc[tid] - m);
    float s = ev;
    __syncthreads();
#pragma unroll
    for (int off = 32; off > 0; off >>= 1) s += __shfl_xor(s, off, 64);
    if (lane == 0) red[wid] = s;
    __syncthreads();
    float tot = 0.f;
#pragma unroll
    for (int i = 0; i < 16; ++i) tot += red[i];
    float inv = __fdividef(1.0f, tot);
    if (tid < T_) {
        float scv = ev * inv;
        scores[b * T_ + tid] = scv;
        sc[tid] = scv;
    }
    __syncthreads();
    float a0 = 0.f, a1 = 0.f, a2 = 0.f, a3 = 0.f;
    const float4* ep = (const float4*)(enc + ((size_t)b * T_ + wid) * 256) + lane;
    for (int t = wid; t < T_; t += 16) {
        float sv = sc[t];
        float4 ev4 = *ep;
        a0 = fmaf(sv, ev4.x, a0);
        a1 = fmaf(sv, ev4.y, a1);
        a2 = fmaf(sv, ev4.z, a2);
        a3 = fmaf(sv, ev4.w, a3);
        ep += 16 * 64;
    }
    part[wid][lane * 4 + 0] = a0;
    part[wid][lane * 4 + 1] = a1;
    part[wid][lane * 4 + 2] = a2;
    part[wid][lane * 4 + 3] = a3;
    __syncthreads();
    if (tid < 256) {
        float c = 0.f;
#pragma unroll
        for (int q = 0; q < 16; ++q) c += part[q][tid];
        ctx_out[b * 256 + tid] = c;
        Xrnn[b * 832 + tid] = c;
    }
}

// ---------------------------------------------------------------------------
// lstm_combine
// ---------------------------------------------------------------------------
__global__ __launch_bounds__(512) void lstm_combine(
    const float* __restrict__ G, const float* __restrict__ bih,
    const float* __restrict__ bhh, const float* __restrict__ c_in,
    const float* __restrict__ x_in, float* __restrict__ h_out,
    float* __restrict__ c_out, float* __restrict__ x_next)
{
    int b = blockIdx.x, j = threadIdx.x;
    size_t base = (size_t)b * 2048;
    float gi = G[base + j] + bih[j] + bhh[j];
    float gf = G[base + 512 + j] + bih[512 + j] + bhh[512 + j];
    float gg = G[base + 1024 + j] + bih[1024 + j] + bhh[1024 + j];
    float go = G[base + 1536 + j] + bih[1536 + j] + bhh[1536 + j];
    float c = fast_sigmoid(gf) * c_in[b * 512 + j] + fast_sigmoid(gi) * fast_tanh(gg);
    float h = fast_sigmoid(go) * fast_tanh(c);
    h_out[b * 512 + j] = h;
    c_out[b * 512 + j] = c;
    x_next[b * 512 + j] = x_in[b * 512 + j] + h;
}

// ---------------------------------------------------------------------------
// mel
// ---------------------------------------------------------------------------
__global__ __launch_bounds__(256) void mel_kernel(
    const float* __restrict__ x2, const float* __restrict__ mel_w,
    int r, float* __restrict__ mels)
{
    __shared__ float xl[512];
    int b = blockIdx.x, tid = threadIdx.x;
    xl[tid] = x2[b * 512 + tid];
    xl[256 + tid] = x2[b * 512 + 256 + tid];
    __syncthreads();
    for (int idx = tid; idx < 80 * r; idx += 256) {
        int mrow = (idx / r) * 10 + (idx % r);
        const float4* w = (const float4*)(mel_w + (size_t)mrow * 512);
        const float4* xv = (const float4*)xl;
        float acc = 0.f;
#pragma unroll 16
        for (int k = 0; k < 128; ++k) {
            float4 a = w[k], c = xv[k];
            acc += a.x * c.x + a.y * c.y + a.z * c.z + a.w * c.w;
        }
        mels[(size_t)b * 80 * r + idx] = acc;
    }
}

// ---------------------------------------------------------------------------
extern "C" void kernel_launch(void* const* d_in, const int* in_sizes, int n_in,
                              void* d_out, int out_size, void* d_ws, size_t ws_size,
                              hipStream_t stream)
{
    const float* enc    = (const float*)d_in[0];
    const float* esp    = (const float*)d_in[1];
    const float* pre_in = (const float*)d_in[2];
    const float* ah_in  = (const float*)d_in[3];
    const float* h1_in  = (const float*)d_in[4];
    const float* h2_in  = (const float*)d_in[5];
    const float* c1_in  = (const float*)d_in[6];
    const float* c2_in  = (const float*)d_in[7];
    const float* ctx_in = (const float*)d_in[8];
    const float* spk    = (const float*)d_in[9];
    const float* noise  = (const float*)d_in[10];
    const float* cum    = (const float*)d_in[11];
    const float* prv    = (const float*)d_in[12];
    const int*   plen   = (const int*)d_in[13];
    const float* fc1_w  = (const float*)d_in[14];
    const float* fc1_b  = (const float*)d_in[15];
    const float* fc2_w  = (const float*)d_in[16];
    const float* fc2_b  = (const float*)d_in[17];
    const float* conv_w = (const float*)d_in[18];
    const float* L_w    = (const float*)d_in[19];
    const float* L_b    = (const float*)d_in[20];
    const float* W_w    = (const float*)d_in[21];
    const float* W_b    = (const float*)d_in[22];
    const float* v_w    = (const float*)d_in[23];
    const float* g_wih  = (const float*)d_in[24];
    const float* g_whh  = (const float*)d_in[25];
    const float* g_bih  = (const float*)d_in[26];
    const float* g_bhh  = (const float*)d_in[27];
    const float* ri_w   = (const float*)d_in[28];
    const float* ri_b   = (const float*)d_in[29];
    const float* l1_wih = (const float*)d_in[30];
    const float* l1_whh = (const float*)d_in[31];
    const float* l1_bih = (const float*)d_in[32];
    const float* l1_bhh = (const float*)d_in[33];
    const float* l2_wih = (const float*)d_in[34];
    const float* l2_whh = (const float*)d_in[35];
    const float* l2_bih = (const float*)d_in[36];
    const float* l2_bhh = (const float*)d_in[37];
    const float* mel_w  = (const float*)d_in[38];

    int r = (out_size - 808960) / 20480;
    if (r < 1) r = 1;
    if (r > 10) r = 10;

    float* out    = (float*)d_out;
    float* mels   = out;
    float* scores = out + (size_t)20480 * r;
    float* ah_out = scores + 153600;
    float* h1_out = ah_out + 65536;
    float* h2_out = h1_out + 131072;
    float* c1_out = h2_out + 131072;
    float* c2_out = c1_out + 131072;
    float* ctx_out = c2_out + 131072;

    float* ws   = (float*)d_ws;
    float* Xgru = ws;                    // 256*640
    float* Cgi  = Xgru + 163840;         // 256*768
    float* Cgh  = Cgi + 196608;
    float* pq   = Cgh + 196608;          // 256*256
    float* uu   = pq + 65536;            // 256*600
    float* Xrnn = uu + 153600;           // 256*832
    float* x0   = Xrnn + 212992;         // 256*512
    float* x1   = x0 + 131072;
    float* x2   = x1 + 131072;
    float* G    = x2 + 131072;           // 256*2048
    ushort* Lw16 = (ushort*)(G + 524288); // 256*32 bf16 = 16 KB

    prenet_kernel<<<256, 256, 0, stream>>>(pre_in, noise, fc1_w, fc1_b, fc2_w, fc2_b,
                                           ctx_in, spk, L_w, Lw16, Xgru, Xrnn);
    gemm_dual<<<dim3(4, 12), 256, 0, stream>>>(Xgru, 640, g_wih, nullptr, 0, nullptr, g_bih, Cgi, 768);
    gemm_dual<<<dim3(4, 12), 256, 0, stream>>>(ah_in, 256, g_whh, nullptr, 0, nullptr, g_bhh, Cgh, 768);
    gru_combine<<<256, 256, 0, stream>>>(Cgi, Cgh, ah_in, ah_out, Xrnn);
    gemm_dual<<<dim3(4, 4), 256, 0, stream>>>(ah_out, 256, W_w, nullptr, 0, nullptr, W_b, pq, 256);
    attn_u_kernel<<<dim3(10, 256), 256, 0, stream>>>(esp, pq, cum, prv, conv_w, Lw16, L_b, v_w, uu);
    softmax_ctx_kernel<<<256, 1024, 0, stream>>>(uu, plen, enc, scores, ctx_out, Xrnn);
    gemm_dual<<<dim3(4, 8), 256, 0, stream>>>(Xrnn, 832, ri_w, nullptr, 0, nullptr, ri_b, x0, 512);
    gemm_dual<<<dim3(4, 32), 256, 0, stream>>>(x0, 512, l1_wih, h1_in, 512, l1_whh, nullptr, G, 2048);
    lstm_combine<<<256, 512, 0, stream>>>(G, l1_bih, l1_bhh, c1_in, x0, h1_out, c1_out, x1);
    gemm_dual<<<dim3(4, 32), 256, 0, stream>>>(x1, 512, l2_wih, h2_in, 512, l2_whh, nullptr, G, 2048);
    lstm_combine<<<256, 512, 0, stream>>>(G, l2_bih, l2_bhh, c2_in, x1, h2_out, c2_out, x2);
    mel_kernel<<<256, 256, 0, stream>>>(x2, mel_w, r, mels);
}

// Round 7
// 274.476 us; speedup vs baseline: 1.7328x; 1.0899x over previous
//
#include <hip/hip_runtime.h>
#include <hip/hip_bf16.h>
#include <cstdint>

#define B_ 256
#define T_ 600
#define D_ 256

typedef __attribute__((ext_vector_type(8))) short bf16x8;
typedef __attribute__((ext_vector_type(4))) float f32x4;

__device__ __forceinline__ float fast_sigmoid(float x) {
    return __fdividef(1.0f, 1.0f + __expf(-x));
}
__device__ __forceinline__ float fast_tanh(float x) {
    return 1.0f - __fdividef(2.0f, __expf(2.0f * x) + 1.0f);
}
__device__ __forceinline__ ushort f2bf(float f) {
    unsigned u = __float_as_uint(f);
    u += 0x7FFF + ((u >> 16) & 1);   // round-to-nearest-even
    return (ushort)(u >> 16);
}

// ---------------------------------------------------------------------------
// prenet (+ fused init_concat + Lw16 bf16 pre-pack by block 0)
// ---------------------------------------------------------------------------
__global__ __launch_bounds__(256) void prenet_kernel(
    const float* __restrict__ pre_in, const float* __restrict__ noise,
    const float* __restrict__ w1, const float* __restrict__ b1,
    const float* __restrict__ w2, const float* __restrict__ b2,
    const float* __restrict__ ctx_in, const float* __restrict__ spk,
    const float* __restrict__ L_w, ushort* __restrict__ Lw16,
    float* __restrict__ Xgru, float* __restrict__ Xrnn)
{
    __shared__ float xin[144];
    __shared__ float p1[256];
    int b = blockIdx.x, t = threadIdx.x;
    if (b == 0) {
#pragma unroll
        for (int i = 0; i < 32; ++i) {
            int idx = i * 256 + t;
            Lw16[idx] = f2bf(L_w[idx]);
        }
    }
    float s = spk[b * 256 + t];
    Xgru[b * 640 + t] = ctx_in[b * 256 + t];
    Xgru[b * 640 + 384 + t] = s;
    Xrnn[b * 832 + 512 + t] = s;
    if (t < 64) Xrnn[b * 832 + 768 + t] = noise[b * 64 + t];
    if (t < 80) xin[t] = pre_in[b * 80 + t];
    else if (t < 144) xin[t] = noise[b * 64 + (t - 80)];
    __syncthreads();
    float acc = b1[t];
    const float4* w = (const float4*)(w1 + t * 144);
    const float4* xi = (const float4*)xin;
#pragma unroll 9
    for (int k = 0; k < 36; ++k) {
        float4 wv = w[k]; float4 xv = xi[k];
        acc += wv.x * xv.x + wv.y * xv.y + wv.z * xv.z + wv.w * xv.w;
    }
    p1[t] = fmaxf(acc, 0.f);
    __syncthreads();
    if (t < 128) {
        float a2 = b2[t];
        const float4* w2v = (const float4*)(w2 + t * 256);
        const float4* pv = (const float4*)p1;
#pragma unroll 8
        for (int k = 0; k < 64; ++k) {
            float4 wv = w2v[k]; float4 xv = pv[k];
            a2 += wv.x * xv.x + wv.y * xv.y + wv.z * xv.z + wv.w * xv.w;
        }
        Xgru[b * 640 + 256 + t] = fmaxf(a2, 0.f);
    }
}

// ---------------------------------------------------------------------------
// gemm32: C[M,N] = A1[M,K1]@B1^T + A2[M,K2]@B2^T (+bias). 32x64 tile,
// 256 threads, acc 4x2/thread, register-prefetch pipeline. 2x the blocks
// of the old 64x64 tile -> fills all 256 CUs on the LSTM gemms.
// ---------------------------------------------------------------------------
__global__ __launch_bounds__(256) void gemm32(
    const float* __restrict__ A1, int K1, const float* __restrict__ B1,
    const float* __restrict__ A2, int K2, const float* __restrict__ B2,
    const float* __restrict__ bias, float* __restrict__ C, int N)
{
    __shared__ float As[16][36];
    __shared__ float Bs[16][68];
    int tid = threadIdx.x;
    int m0 = blockIdx.x * 32, n0 = blockIdx.y * 64;
    int tm = tid & 7, tn = tid >> 3;          // out: rows tm*4..+3, cols tn*2..+1
    int lr = tid >> 2, lq = tid & 3;          // B loader: row lr (0..63), quad lq
    int ar = (tid & 127) >> 2;                // A loader: row 0..31
    float acc[4][2] = {};
    int nkt = (K1 + K2) >> 4;

    float4 av, bv;
    {
        const float* A; const float* Bb; int kk; int K;
        if (0 < K1) { A = A1; Bb = B1; kk = 0; K = K1; }
        else        { A = A2; Bb = B2; kk = -K1; K = K2; }
        if (tid < 128) av = *(const float4*)&A[(size_t)(m0 + ar) * K + kk + lq * 4];
        bv = *(const float4*)&Bb[(size_t)(n0 + lr) * K + kk + lq * 4];
    }
    for (int kt = 0; kt < nkt; ++kt) {
        __syncthreads();
        if (tid < 128) {
            As[lq * 4 + 0][ar] = av.x; As[lq * 4 + 1][ar] = av.y;
            As[lq * 4 + 2][ar] = av.z; As[lq * 4 + 3][ar] = av.w;
        }
        Bs[lq * 4 + 0][lr] = bv.x; Bs[lq * 4 + 1][lr] = bv.y;
        Bs[lq * 4 + 2][lr] = bv.z; Bs[lq * 4 + 3][lr] = bv.w;
        __syncthreads();
        if (kt + 1 < nkt) {
            int kg = (kt + 1) << 4;
            const float* A; const float* Bb; int kk; int K;
            if (kg < K1) { A = A1; Bb = B1; kk = kg; K = K1; }
            else         { A = A2; Bb = B2; kk = kg - K1; K = K2; }
            if (tid < 128) av = *(const float4*)&A[(size_t)(m0 + ar) * K + kk + lq * 4];
            bv = *(const float4*)&Bb[(size_t)(n0 + lr) * K + kk + lq * 4];
        }
#pragma unroll
        for (int k = 0; k < 16; ++k) {
            float4 a = *(const float4*)&As[k][tm * 4];
            float2 b = *(const float2*)&Bs[k][tn * 2];
            acc[0][0] = fmaf(a.x, b.x, acc[0][0]);
            acc[0][1] = fmaf(a.x, b.y, acc[0][1]);
            acc[1][0] = fmaf(a.y, b.x, acc[1][0]);
            acc[1][1] = fmaf(a.y, b.y, acc[1][1]);
            acc[2][0] = fmaf(a.z, b.x, acc[2][0]);
            acc[2][1] = fmaf(a.z, b.y, acc[2][1]);
            acc[3][0] = fmaf(a.w, b.x, acc[3][0]);
            acc[3][1] = fmaf(a.w, b.y, acc[3][1]);
        }
    }
    float b0 = 0.f, b1v = 0.f;
    if (bias) { b0 = bias[n0 + tn * 2]; b1v = bias[n0 + tn * 2 + 1]; }
#pragma unroll
    for (int i = 0; i < 4; ++i) {
        float2 o = make_float2(acc[i][0] + b0, acc[i][1] + b1v);
        *(float2*)&C[(size_t)(m0 + tm * 4 + i) * N + n0 + tn * 2] = o;
    }
}

// ---------------------------------------------------------------------------
// gru_combine
// ---------------------------------------------------------------------------
__global__ __launch_bounds__(256) void gru_combine(
    const float* __restrict__ Cgi, const float* __restrict__ Cgh,
    const float* __restrict__ h_in, float* __restrict__ ah_out,
    float* __restrict__ Xrnn)
{
    int b = blockIdx.x, j = threadIdx.x;
    float gir = Cgi[b * 768 + j], giz = Cgi[b * 768 + 256 + j], gin = Cgi[b * 768 + 512 + j];
    float ghr = Cgh[b * 768 + j], ghz = Cgh[b * 768 + 256 + j], ghn = Cgh[b * 768 + 512 + j];
    float rr = fast_sigmoid(gir + ghr);
    float zz = fast_sigmoid(giz + ghz);
    float nn = fast_tanh(gin + rr * ghn);
    float h = (1.f - zz) * nn + zz * h_in[b * 256 + j];
    ah_out[b * 256 + j] = h;
    Xrnn[b * 832 + 256 + j] = h;
}

// ---------------------------------------------------------------------------
// fused_attn: pq-projection + conv + location-score + softmax + context,
// one block per batch row b. 512 threads = 8 waves. T processed in 5
// superchunks of 128 t (8 waves x 16 t MFMA tiles).
// ---------------------------------------------------------------------------
#define FT 512
__global__ __launch_bounds__(512) void fused_attn_kernel(
    const float* __restrict__ esp, const float* __restrict__ enc,
    const float* __restrict__ ah, const float* __restrict__ W_w,
    const float* __restrict__ W_b,
    const float* __restrict__ cum, const float* __restrict__ prv,
    const float* __restrict__ conv_w, const ushort* __restrict__ Lw16,
    const float* __restrict__ L_b, const float* __restrict__ v_w,
    const int* __restrict__ plen,
    float* __restrict__ scores, float* __restrict__ ctx_out,
    float* __restrict__ Xrnn)
{
    __shared__ float cumF[672], prvF[672];   // idx i -> t = i-15 (zero-padded)
    __shared__ float cwL[1984];
    __shared__ ushort locs[128][32];
    __shared__ float pq2s[256], vvs[256], ahL[256];
    __shared__ float pqp[2][256];
    __shared__ float uL[600];
    __shared__ float redm[8], reds[8];
    __shared__ float part[8][256];

    int b = blockIdx.x;
    int tid = threadIdx.x;
    int lane = tid & 63, wv = tid >> 6;
    int cl = lane & 15, gr = lane >> 4;
    int f = tid & 31, ts = tid >> 5;         // conv role: filter f, t-group ts (0..15)

    // ---- stage (cum/prv halo rows, conv weights, v, ah) + afr global loads
    for (int i = tid; i < 672; i += FT) {
        int tg = i - 15;
        bool ok = (tg >= 0) && (tg < T_);
        cumF[i] = ok ? cum[b * T_ + tg] : 0.f;
        prvF[i] = ok ? prv[b * T_ + tg] : 0.f;
    }
    for (int i = tid; i < 1984; i += FT) cwL[i] = conv_w[i];
    if (tid < 256) { vvs[tid] = v_w[tid]; ahL[tid] = ah[b * 256 + tid]; }
    bf16x8 afr[16];
#pragma unroll
    for (int dt = 0; dt < 16; ++dt)
        afr[dt] = *(const bf16x8*)&Lw16[(dt * 16 + cl) * 32 + gr * 8];
    __syncthreads();

    // conv weights into registers (persist across superchunks)
    float wc[31], wp[31];
#pragma unroll
    for (int k = 0; k < 31; ++k) { wc[k] = cwL[f * 62 + k]; wp[k] = cwL[f * 62 + 31 + k]; }

    auto conv_phase = [&](int sc) {
        int tb = sc * 128 + ts * 8;
        float winc[38], winp[38];
#pragma unroll
        for (int k = 0; k < 38; ++k) { winc[k] = cumF[tb + k]; winp[k] = prvF[tb + k]; }
        float acc[8] = {};
#pragma unroll
        for (int i = 0; i < 8; ++i)
#pragma unroll
            for (int k = 0; k < 31; ++k)
                acc[i] = fmaf(winc[i + k], wc[k], fmaf(winp[i + k], wp[k], acc[i]));
#pragma unroll
        for (int i = 0; i < 8; ++i)
            locs[ts * 8 + i][f] = f2bf(acc[i]);
    };

    // pq half-dot (d = tid&255, half = tid>>8) + conv(0)
    {
        int d = tid & 255, hf = tid >> 8;
        const float4* wr = (const float4*)(W_w + (size_t)d * 256 + hf * 128);
        const float4* arp = (const float4*)(ahL + hf * 128);
        float acc = 0.f;
#pragma unroll
        for (int k = 0; k < 32; ++k) {
            float4 w4 = wr[k], a4 = arp[k];
            acc += w4.x * a4.x + w4.y * a4.y + w4.z * a4.z + w4.w * a4.w;
        }
        pqp[hf][d] = acc;
    }
    conv_phase(0);
    __syncthreads();
    if (tid < 256) pq2s[tid] = pqp[0][tid] + pqp[1][tid] + W_b[tid] + L_b[tid];
    __syncthreads();

    // ---- superchunk loop: esp/MFMA on sc, then conv for sc+1
    for (int sc = 0; sc < 5; ++sc) {
        int twl = sc * 128 + wv * 16 + cl;
        int tc = (twl < T_) ? twl : (T_ - 1);
        bf16x8 locf = *(const bf16x8*)&locs[wv * 16 + cl][gr * 8];
        const float4* ep4 = (const float4*)(esp + ((size_t)b * T_ + tc) * 256) + gr;
        float sum = 0.f;
#pragma unroll
        for (int dt = 0; dt < 16; ++dt) {
            float4 pq4 = *(const float4*)&pq2s[dt * 16 + gr * 4];
            float4 vv4 = *(const float4*)&vvs[dt * 16 + gr * 4];
            float4 e4 = ep4[dt * 4];
            f32x4 acc = {pq4.x, pq4.y, pq4.z, pq4.w};
            acc = __builtin_amdgcn_mfma_f32_16x16x32_bf16(afr[dt], locf, acc, 0, 0, 0);
            sum = fmaf(fast_tanh(e4.x + acc[0]), vv4.x, sum);
            sum = fmaf(fast_tanh(e4.y + acc[1]), vv4.y, sum);
            sum = fmaf(fast_tanh(e4.z + acc[2]), vv4.z, sum);
            sum = fmaf(fast_tanh(e4.w + acc[3]), vv4.w, sum);
        }
        sum += __shfl_xor(sum, 16, 64);
        sum += __shfl_xor(sum, 32, 64);
        if (lane < 16 && twl < T_) uL[twl] = sum;
        __syncthreads();
        if (sc < 4) {
            conv_phase(sc + 1);
            __syncthreads();
        }
    }

    // ---- softmax over uL (mask t >= plen)
    int pl = plen[b];
    float m = -1e30f;
    for (int i = tid; i < T_; i += FT) {
        float x = (i < pl) ? uL[i] : -1e9f;
        uL[i] = x;
        m = fmaxf(m, x);
    }
#pragma unroll
    for (int off = 32; off > 0; off >>= 1) m = fmaxf(m, __shfl_xor(m, off, 64));
    if (lane == 0) redm[wv] = m;
    __syncthreads();
    m = redm[0];
#pragma unroll
    for (int i = 1; i < 8; ++i) m = fmaxf(m, redm[i]);
    float s = 0.f;
    for (int i = tid; i < T_; i += FT) {
        float e = __expf(uL[i] - m);
        uL[i] = e;
        s += e;
    }
#pragma unroll
    for (int off = 32; off > 0; off >>= 1) s += __shfl_xor(s, off, 64);
    if (lane == 0) reds[wv] = s;
    __syncthreads();
    float tot = 0.f;
#pragma unroll
    for (int i = 0; i < 8; ++i) tot += reds[i];
    float inv = __fdividef(1.0f, tot);
    for (int i = tid; i < T_; i += FT) {
        float p = uL[i] * inv;
        uL[i] = p;
        scores[b * T_ + i] = p;
    }
    __syncthreads();

    // ---- context: wave wv handles t = wv, wv+8, ...; lane holds d-quad
    float a0 = 0.f, a1 = 0.f, a2 = 0.f, a3 = 0.f;
    const float4* ep = (const float4*)(enc + ((size_t)b * T_ + wv) * 256) + lane;
    for (int t = wv; t < T_; t += 8) {
        float sv = uL[t];
        float4 e4 = *ep;
        a0 = fmaf(sv, e4.x, a0);
        a1 = fmaf(sv, e4.y, a1);
        a2 = fmaf(sv, e4.z, a2);
        a3 = fmaf(sv, e4.w, a3);
        ep += 8 * 64;
    }
    part[wv][lane * 4 + 0] = a0;
    part[wv][lane * 4 + 1] = a1;
    part[wv][lane * 4 + 2] = a2;
    part[wv][lane * 4 + 3] = a3;
    __syncthreads();
    if (tid < 256) {
        float c = 0.f;
#pragma unroll
        for (int q = 0; q < 8; ++q) c += part[q][tid];
        ctx_out[b * 256 + tid] = c;
        Xrnn[b * 832 + tid] = c;
    }
}

// ---------------------------------------------------------------------------
// lstm_combine
// ---------------------------------------------------------------------------
__global__ __launch_bounds__(512) void lstm_combine(
    const float* __restrict__ G, const float* __restrict__ bih,
    const float* __restrict__ bhh, const float* __restrict__ c_in,
    const float* __restrict__ x_in, float* __restrict__ h_out,
    float* __restrict__ c_out, float* __restrict__ x_next)
{
    int b = blockIdx.x, j = threadIdx.x;
    size_t base = (size_t)b * 2048;
    float gi = G[base + j] + bih[j] + bhh[j];
    float gf = G[base + 512 + j] + bih[512 + j] + bhh[512 + j];
    float gg = G[base + 1024 + j] + bih[1024 + j] + bhh[1024 + j];
    float go = G[base + 1536 + j] + bih[1536 + j] + bhh[1536 + j];
    float c = fast_sigmoid(gf) * c_in[b * 512 + j] + fast_sigmoid(gi) * fast_tanh(gg);
    float h = fast_sigmoid(go) * fast_tanh(c);
    h_out[b * 512 + j] = h;
    c_out[b * 512 + j] = c;
    x_next[b * 512 + j] = x_in[b * 512 + j] + h;
}

// ---------------------------------------------------------------------------
// mel
// ---------------------------------------------------------------------------
__global__ __launch_bounds__(256) void mel_kernel(
    const float* __restrict__ x2, const float* __restrict__ mel_w,
    int r, float* __restrict__ mels)
{
    __shared__ float xl[512];
    int b = blockIdx.x, tid = threadIdx.x;
    xl[tid] = x2[b * 512 + tid];
    xl[256 + tid] = x2[b * 512 + 256 + tid];
    __syncthreads();
    for (int idx = tid; idx < 80 * r; idx += 256) {
        int mrow = (idx / r) * 10 + (idx % r);
        const float4* w = (const float4*)(mel_w + (size_t)mrow * 512);
        const float4* xv = (const float4*)xl;
        float acc = 0.f;
#pragma unroll 16
        for (int k = 0; k < 128; ++k) {
            float4 a = w[k], c = xv[k];
            acc += a.x * c.x + a.y * c.y + a.z * c.z + a.w * c.w;
        }
        mels[(size_t)b * 80 * r + idx] = acc;
    }
}

// ---------------------------------------------------------------------------
extern "C" void kernel_launch(void* const* d_in, const int* in_sizes, int n_in,
                              void* d_out, int out_size, void* d_ws, size_t ws_size,
                              hipStream_t stream)
{
    const float* enc    = (const float*)d_in[0];
    const float* esp    = (const float*)d_in[1];
    const float* pre_in = (const float*)d_in[2];
    const float* ah_in  = (const float*)d_in[3];
    const float* h1_in  = (const float*)d_in[4];
    const float* h2_in  = (const float*)d_in[5];
    const float* c1_in  = (const float*)d_in[6];
    const float* c2_in  = (const float*)d_in[7];
    const float* ctx_in = (const float*)d_in[8];
    const float* spk    = (const float*)d_in[9];
    const float* noise  = (const float*)d_in[10];
    const float* cum    = (const float*)d_in[11];
    const float* prv    = (const float*)d_in[12];
    const int*   plen   = (const int*)d_in[13];
    const float* fc1_w  = (const float*)d_in[14];
    const float* fc1_b  = (const float*)d_in[15];
    const float* fc2_w  = (const float*)d_in[16];
    const float* fc2_b  = (const float*)d_in[17];
    const float* conv_w = (const float*)d_in[18];
    const float* L_w    = (const float*)d_in[19];
    const float* L_b    = (const float*)d_in[20];
    const float* W_w    = (const float*)d_in[21];
    const float* W_b    = (const float*)d_in[22];
    const float* v_w    = (const float*)d_in[23];
    const float* g_wih  = (const float*)d_in[24];
    const float* g_whh  = (const float*)d_in[25];
    const float* g_bih  = (const float*)d_in[26];
    const float* g_bhh  = (const float*)d_in[27];
    const float* ri_w   = (const float*)d_in[28];
    const float* ri_b   = (const float*)d_in[29];
    const float* l1_wih = (const float*)d_in[30];
    const float* l1_whh = (const float*)d_in[31];
    const float* l1_bih = (const float*)d_in[32];
    const float* l1_bhh = (const float*)d_in[33];
    const float* l2_wih = (const float*)d_in[34];
    const float* l2_whh = (const float*)d_in[35];
    const float* l2_bih = (const float*)d_in[36];
    const float* l2_bhh = (const float*)d_in[37];
    const float* mel_w  = (const float*)d_in[38];

    int r = (out_size - 808960) / 20480;
    if (r < 1) r = 1;
    if (r > 10) r = 10;

    float* out    = (float*)d_out;
    float* mels   = out;
    float* scores = out + (size_t)20480 * r;
    float* ah_out = scores + 153600;
    float* h1_out = ah_out + 65536;
    float* h2_out = h1_out + 131072;
    float* c1_out = h2_out + 131072;
    float* c2_out = c1_out + 131072;
    float* ctx_out = c2_out + 131072;

    float* ws   = (float*)d_ws;
    float* Xgru = ws;                    // 256*640
    float* Cgi  = Xgru + 163840;         // 256*768
    float* Cgh  = Cgi + 196608;
    float* pq   = Cgh + 196608;          // (unused now)
    float* uu   = pq + 65536;            // (unused now)
    float* Xrnn = uu + 153600;           // 256*832
    float* x0   = Xrnn + 212992;         // 256*512
    float* x1   = x0 + 131072;
    float* x2   = x1 + 131072;
    float* G    = x2 + 131072;           // 256*2048
    ushort* Lw16 = (ushort*)(G + 524288); // 256*32 bf16 = 16 KB

    prenet_kernel<<<256, 256, 0, stream>>>(pre_in, noise, fc1_w, fc1_b, fc2_w, fc2_b,
                                           ctx_in, spk, L_w, Lw16, Xgru, Xrnn);
    gemm32<<<dim3(8, 12), 256, 0, stream>>>(Xgru, 640, g_wih, nullptr, 0, nullptr, g_bih, Cgi, 768);
    gemm32<<<dim3(8, 12), 256, 0, stream>>>(ah_in, 256, g_whh, nullptr, 0, nullptr, g_bhh, Cgh, 768);
    gru_combine<<<256, 256, 0, stream>>>(Cgi, Cgh, ah_in, ah_out, Xrnn);
    fused_attn_kernel<<<256, 512, 0, stream>>>(esp, enc, ah_out, W_w, W_b, cum, prv,
                                               conv_w, Lw16, L_b, v_w, plen,
                                               scores, ctx_out, Xrnn);
    gemm32<<<dim3(8, 8), 256, 0, stream>>>(Xrnn, 832, ri_w, nullptr, 0, nullptr, ri_b, x0, 512);
    gemm32<<<dim3(8, 32), 256, 0, stream>>>(x0, 512, l1_wih, h1_in, 512, l1_whh, nullptr, G, 2048);
    lstm_combine<<<256, 512, 0, stream>>>(G, l1_bih, l1_bhh, c1_in, x0, h1_out, c1_out, x1);
    gemm32<<<dim3(8, 32), 256, 0, stream>>>(x1, 512, l2_wih, h2_in, 512, l2_whh, nullptr, G, 2048);
    lstm_combine<<<256, 512, 0, stream>>>(G, l2_bih, l2_bhh, c2_in, x1, h2_out, c2_out, x2);
    mel_kernel<<<256, 256, 0, stream>>>(x2, mel_w, r, mels);
}

// Round 8
// 263.415 us; speedup vs baseline: 1.8056x; 1.0420x over previous
//
#include <hip/hip_runtime.h>
#include <hip/hip_bf16.h>
#include <cstdint>

#define B_ 256
#define T_ 600
#define D_ 256

typedef __attribute__((ext_vector_type(8))) short bf16x8;
typedef __attribute__((ext_vector_type(4))) float f32x4;

__device__ __forceinline__ float fast_sigmoid(float x) {
    return __fdividef(1.0f, 1.0f + __expf(-x));
}
__device__ __forceinline__ float fast_tanh(float x) {
    return 1.0f - __fdividef(2.0f, __expf(2.0f * x) + 1.0f);
}
__device__ __forceinline__ ushort f2bf(float f) {
    unsigned u = __float_as_uint(f);
    u += 0x7FFF + ((u >> 16) & 1);   // round-to-nearest-even
    return (ushort)(u >> 16);
}

// ---------------------------------------------------------------------------
// prenet (+ fused init_concat + Lw16 bf16 pre-pack by block 0)
// ---------------------------------------------------------------------------
__global__ __launch_bounds__(256) void prenet_kernel(
    const float* __restrict__ pre_in, const float* __restrict__ noise,
    const float* __restrict__ w1, const float* __restrict__ b1,
    const float* __restrict__ w2, const float* __restrict__ b2,
    const float* __restrict__ ctx_in, const float* __restrict__ spk,
    const float* __restrict__ L_w, ushort* __restrict__ Lw16,
    float* __restrict__ Xgru, float* __restrict__ Xrnn)
{
    __shared__ float xin[144];
    __shared__ float p1[256];
    int b = blockIdx.x, t = threadIdx.x;
    if (b == 0) {
#pragma unroll
        for (int i = 0; i < 32; ++i) {
            int idx = i * 256 + t;
            Lw16[idx] = f2bf(L_w[idx]);
        }
    }
    float s = spk[b * 256 + t];
    Xgru[b * 640 + t] = ctx_in[b * 256 + t];
    Xgru[b * 640 + 384 + t] = s;
    Xrnn[b * 832 + 512 + t] = s;
    if (t < 64) Xrnn[b * 832 + 768 + t] = noise[b * 64 + t];
    if (t < 80) xin[t] = pre_in[b * 80 + t];
    else if (t < 144) xin[t] = noise[b * 64 + (t - 80)];
    __syncthreads();
    float acc = b1[t];
    const float4* w = (const float4*)(w1 + t * 144);
    const float4* xi = (const float4*)xin;
#pragma unroll 9
    for (int k = 0; k < 36; ++k) {
        float4 wv = w[k]; float4 xv = xi[k];
        acc += wv.x * xv.x + wv.y * xv.y + wv.z * xv.z + wv.w * xv.w;
    }
    p1[t] = fmaxf(acc, 0.f);
    __syncthreads();
    if (t < 128) {
        float a2 = b2[t];
        const float4* w2v = (const float4*)(w2 + t * 256);
        const float4* pv = (const float4*)p1;
#pragma unroll 8
        for (int k = 0; k < 64; ++k) {
            float4 wv = w2v[k]; float4 xv = pv[k];
            a2 += wv.x * xv.x + wv.y * xv.y + wv.z * xv.z + wv.w * xv.w;
        }
        Xgru[b * 640 + 256 + t] = fmaxf(a2, 0.f);
    }
}

// ---------------------------------------------------------------------------
// gemm32: C[M,N] = A1[M,K1]@B1^T + A2[M,K2]@B2^T (+bias). 32x64 tile,
// 256 threads, acc 4x2/thread, register-prefetch pipeline.
// ---------------------------------------------------------------------------
__global__ __launch_bounds__(256) void gemm32(
    const float* __restrict__ A1, int K1, const float* __restrict__ B1,
    const float* __restrict__ A2, int K2, const float* __restrict__ B2,
    const float* __restrict__ bias, float* __restrict__ C, int N)
{
    __shared__ float As[16][36];
    __shared__ float Bs[16][68];
    int tid = threadIdx.x;
    int m0 = blockIdx.x * 32, n0 = blockIdx.y * 64;
    int tm = tid & 7, tn = tid >> 3;
    int lr = tid >> 2, lq = tid & 3;
    int ar = (tid & 127) >> 2;
    float acc[4][2] = {};
    int nkt = (K1 + K2) >> 4;

    float4 av, bv;
    {
        const float* A; const float* Bb; int kk; int K;
        if (0 < K1) { A = A1; Bb = B1; kk = 0; K = K1; }
        else        { A = A2; Bb = B2; kk = -K1; K = K2; }
        if (tid < 128) av = *(const float4*)&A[(size_t)(m0 + ar) * K + kk + lq * 4];
        bv = *(const float4*)&Bb[(size_t)(n0 + lr) * K + kk + lq * 4];
    }
    for (int kt = 0; kt < nkt; ++kt) {
        __syncthreads();
        if (tid < 128) {
            As[lq * 4 + 0][ar] = av.x; As[lq * 4 + 1][ar] = av.y;
            As[lq * 4 + 2][ar] = av.z; As[lq * 4 + 3][ar] = av.w;
        }
        Bs[lq * 4 + 0][lr] = bv.x; Bs[lq * 4 + 1][lr] = bv.y;
        Bs[lq * 4 + 2][lr] = bv.z; Bs[lq * 4 + 3][lr] = bv.w;
        __syncthreads();
        if (kt + 1 < nkt) {
            int kg = (kt + 1) << 4;
            const float* A; const float* Bb; int kk; int K;
            if (kg < K1) { A = A1; Bb = B1; kk = kg; K = K1; }
            else         { A = A2; Bb = B2; kk = kg - K1; K = K2; }
            if (tid < 128) av = *(const float4*)&A[(size_t)(m0 + ar) * K + kk + lq * 4];
            bv = *(const float4*)&Bb[(size_t)(n0 + lr) * K + kk + lq * 4];
        }
#pragma unroll
        for (int k = 0; k < 16; ++k) {
            float4 a = *(const float4*)&As[k][tm * 4];
            float2 b = *(const float2*)&Bs[k][tn * 2];
            acc[0][0] = fmaf(a.x, b.x, acc[0][0]);
            acc[0][1] = fmaf(a.x, b.y, acc[0][1]);
            acc[1][0] = fmaf(a.y, b.x, acc[1][0]);
            acc[1][1] = fmaf(a.y, b.y, acc[1][1]);
            acc[2][0] = fmaf(a.z, b.x, acc[2][0]);
            acc[2][1] = fmaf(a.z, b.y, acc[2][1]);
            acc[3][0] = fmaf(a.w, b.x, acc[3][0]);
            acc[3][1] = fmaf(a.w, b.y, acc[3][1]);
        }
    }
    float b0 = 0.f, b1v = 0.f;
    if (bias) { b0 = bias[n0 + tn * 2]; b1v = bias[n0 + tn * 2 + 1]; }
#pragma unroll
    for (int i = 0; i < 4; ++i) {
        float2 o = make_float2(acc[i][0] + b0, acc[i][1] + b1v);
        *(float2*)&C[(size_t)(m0 + tm * 4 + i) * N + n0 + tn * 2] = o;
    }
}

// ---------------------------------------------------------------------------
// gru_combine
// ---------------------------------------------------------------------------
__global__ __launch_bounds__(256) void gru_combine(
    const float* __restrict__ Cgi, const float* __restrict__ Cgh,
    const float* __restrict__ h_in, float* __restrict__ ah_out,
    float* __restrict__ Xrnn)
{
    int b = blockIdx.x, j = threadIdx.x;
    float gir = Cgi[b * 768 + j], giz = Cgi[b * 768 + 256 + j], gin = Cgi[b * 768 + 512 + j];
    float ghr = Cgh[b * 768 + j], ghz = Cgh[b * 768 + 256 + j], ghn = Cgh[b * 768 + 512 + j];
    float rr = fast_sigmoid(gir + ghr);
    float zz = fast_sigmoid(giz + ghz);
    float nn = fast_tanh(gin + rr * ghn);
    float h = (1.f - zz) * nn + zz * h_in[b * 256 + j];
    ah_out[b * 256 + j] = h;
    Xrnn[b * 832 + 256 + j] = h;
}

// ---------------------------------------------------------------------------
// attn_u v6 (re-instated): swapped-operand MFMA (C[d][t]) -> float4 esp loads.
// grid (10 chunks of 64 t, B), 256 threads = 4 waves x 16 t. No cross-phase
// serialization across blocks -> 10 independent blocks/CU hide HBM latency.
// ---------------------------------------------------------------------------
#define TCH 64
__global__ __launch_bounds__(256) void attn_u_kernel(
    const float* __restrict__ esp, const float* __restrict__ pq,
    const float* __restrict__ cum, const float* __restrict__ prv,
    const float* __restrict__ conv_w, const ushort* __restrict__ Lw16,
    const float* __restrict__ L_b, const float* __restrict__ v_w,
    float* __restrict__ u)
{
    __shared__ float cumL[TCH + 32], prvL[TCH + 32];
    __shared__ float cwL[32 * 62];
    __shared__ ushort locs[TCH][32];
    __shared__ float pq2s[256], vvs[256];
    int b = blockIdx.y;
    int t0 = blockIdx.x * TCH;
    int tid = threadIdx.x;

    for (int i = tid; i < TCH + 30; i += 256) {
        int tg = t0 + i - 15;
        bool ok = (tg >= 0) && (tg < T_);
        cumL[i] = ok ? cum[b * T_ + tg] : 0.f;
        prvL[i] = ok ? prv[b * T_ + tg] : 0.f;
    }
    for (int i = tid; i < 32 * 62; i += 256) cwL[i] = conv_w[i];
    pq2s[tid] = pq[b * 256 + tid] + L_b[tid];
    vvs[tid] = v_w[tid];
    __syncthreads();

    {
        int f = tid & 31, ts = tid >> 5;
        float wc[31], wp[31];
#pragma unroll
        for (int k = 0; k < 31; ++k) {
            wc[k] = cwL[f * 62 + k];
            wp[k] = cwL[f * 62 + 31 + k];
        }
        float winc[38], winp[38];
#pragma unroll
        for (int k = 0; k < 38; ++k) {
            winc[k] = cumL[ts * 8 + k];
            winp[k] = prvL[ts * 8 + k];
        }
        float acc[8] = {};
#pragma unroll
        for (int i = 0; i < 8; ++i)
#pragma unroll
            for (int k = 0; k < 31; ++k)
                acc[i] = fmaf(winc[i + k], wc[k], fmaf(winp[i + k], wp[k], acc[i]));
#pragma unroll
        for (int i = 0; i < 8; ++i)
            locs[ts * 8 + i][f] = f2bf(acc[i]);
    }

    int lane = tid & 63, wv = tid >> 6;
    int cl = lane & 15, gr = lane >> 4;
    bf16x8 afr[16];
#pragma unroll
    for (int dt = 0; dt < 16; ++dt)
        afr[dt] = *(const bf16x8*)&Lw16[(dt * 16 + cl) * 32 + gr * 8];
    __syncthreads();

    int tw = t0 + wv * 16 + cl;
    int tc = (tw < T_) ? tw : (T_ - 1);
    bf16x8 locf = *(const bf16x8*)&locs[wv * 16 + cl][gr * 8];
    const float4* ep4 = (const float4*)(esp + ((size_t)b * T_ + tc) * 256) + gr;

    float sum = 0.f;
#pragma unroll
    for (int dt = 0; dt < 16; ++dt) {
        float4 pq4 = *(const float4*)&pq2s[dt * 16 + gr * 4];
        float4 vv4 = *(const float4*)&vvs[dt * 16 + gr * 4];
        float4 e4 = ep4[dt * 4];
        f32x4 acc = {pq4.x, pq4.y, pq4.z, pq4.w};
        acc = __builtin_amdgcn_mfma_f32_16x16x32_bf16(afr[dt], locf, acc, 0, 0, 0);
        sum = fmaf(fast_tanh(e4.x + acc[0]), vv4.x, sum);
        sum = fmaf(fast_tanh(e4.y + acc[1]), vv4.y, sum);
        sum = fmaf(fast_tanh(e4.z + acc[2]), vv4.z, sum);
        sum = fmaf(fast_tanh(e4.w + acc[3]), vv4.w, sum);
    }
    sum += __shfl_xor(sum, 16, 64);
    sum += __shfl_xor(sum, 32, 64);
    if (lane < 16 && tw < T_) u[b * T_ + tw] = sum;
}

// ---------------------------------------------------------------------------
// softmax + context (1024 threads = 16 waves/CU for enc streaming)
// ---------------------------------------------------------------------------
__global__ __launch_bounds__(1024) void softmax_ctx_kernel(
    const float* __restrict__ u, const int* __restrict__ plen,
    const float* __restrict__ enc,
    float* __restrict__ scores, float* __restrict__ ctx_out,
    float* __restrict__ Xrnn)
{
    __shared__ float sc[T_];
    __shared__ float red[16];
    __shared__ float part[16][256];
    int b = blockIdx.x, tid = threadIdx.x;
    int lane = tid & 63, wid = tid >> 6;
    int pl = plen[b];
    float mv = -1e30f;
    if (tid < T_) {
        float uv = u[b * T_ + tid];
        mv = (tid < pl) ? uv : -1e9f;
        sc[tid] = mv;
    }
    float m = mv;
#pragma unroll
    for (int off = 32; off > 0; off >>= 1) m = fmaxf(m, __shfl_xor(m, off, 64));
    if (lane == 0) red[wid] = m;
    __syncthreads();
    m = red[0];
#pragma unroll
    for (int i = 1; i < 16; ++i) m = fmaxf(m, red[i]);
    float ev = 0.f;
    if (tid < T_) ev = __expf(sc[tid] - m);
    float s = ev;
    __syncthreads();
#pragma unroll
    for (int off = 32; off > 0; off >>= 1) s += __shfl_xor(s, off, 64);
    if (lane == 0) red[wid] = s;
    __syncthreads();
    float tot = 0.f;
#pragma unroll
    for (int i = 0; i < 16; ++i) tot += red[i];
    float inv = __fdividef(1.0f, tot);
    if (tid < T_) {
        float scv = ev * inv;
        scores[b * T_ + tid] = scv;
        sc[tid] = scv;
    }
    __syncthreads();
    float a0 = 0.f, a1 = 0.f, a2 = 0.f, a3 = 0.f;
    const float4* ep = (const float4*)(enc + ((size_t)b * T_ + wid) * 256) + lane;
    for (int t = wid; t < T_; t += 16) {
        float sv = sc[t];
        float4 ev4 = *ep;
        a0 = fmaf(sv, ev4.x, a0);
        a1 = fmaf(sv, ev4.y, a1);
        a2 = fmaf(sv, ev4.z, a2);
        a3 = fmaf(sv, ev4.w, a3);
        ep += 16 * 64;
    }
    part[wid][lane * 4 + 0] = a0;
    part[wid][lane * 4 + 1] = a1;
    part[wid][lane * 4 + 2] = a2;
    part[wid][lane * 4 + 3] = a3;
    __syncthreads();
    if (tid < 256) {
        float c = 0.f;
#pragma unroll
        for (int q = 0; q < 16; ++q) c += part[q][tid];
        ctx_out[b * 256 + tid] = c;
        Xrnn[b * 832 + tid] = c;
    }
}

// ---------------------------------------------------------------------------
// lstm_combine
// ---------------------------------------------------------------------------
__global__ __launch_bounds__(512) void lstm_combine(
    const float* __restrict__ G, const float* __restrict__ bih,
    const float* __restrict__ bhh, const float* __restrict__ c_in,
    const float* __restrict__ x_in, float* __restrict__ h_out,
    float* __restrict__ c_out, float* __restrict__ x_next)
{
    int b = blockIdx.x, j = threadIdx.x;
    size_t base = (size_t)b * 2048;
    float gi = G[base + j] + bih[j] + bhh[j];
    float gf = G[base + 512 + j] + bih[512 + j] + bhh[512 + j];
    float gg = G[base + 1024 + j] + bih[1024 + j] + bhh[1024 + j];
    float go = G[base + 1536 + j] + bih[1536 + j] + bhh[1536 + j];
    float c = fast_sigmoid(gf) * c_in[b * 512 + j] + fast_sigmoid(gi) * fast_tanh(gg);
    float h = fast_sigmoid(go) * fast_tanh(c);
    h_out[b * 512 + j] = h;
    c_out[b * 512 + j] = c;
    x_next[b * 512 + j] = x_in[b * 512 + j] + h;
}

// ---------------------------------------------------------------------------
// mel
// ---------------------------------------------------------------------------
__global__ __launch_bounds__(256) void mel_kernel(
    const float* __restrict__ x2, const float* __restrict__ mel_w,
    int r, float* __restrict__ mels)
{
    __shared__ float xl[512];
    int b = blockIdx.x, tid = threadIdx.x;
    xl[tid] = x2[b * 512 + tid];
    xl[256 + tid] = x2[b * 512 + 256 + tid];
    __syncthreads();
    for (int idx = tid; idx < 80 * r; idx += 256) {
        int mrow = (idx / r) * 10 + (idx % r);
        const float4* w = (const float4*)(mel_w + (size_t)mrow * 512);
        const float4* xv = (const float4*)xl;
        float acc = 0.f;
#pragma unroll 16
        for (int k = 0; k < 128; ++k) {
            float4 a = w[k], c = xv[k];
            acc += a.x * c.x + a.y * c.y + a.z * c.z + a.w * c.w;
        }
        mels[(size_t)b * 80 * r + idx] = acc;
    }
}

// ---------------------------------------------------------------------------
extern "C" void kernel_launch(void* const* d_in, const int* in_sizes, int n_in,
                              void* d_out, int out_size, void* d_ws, size_t ws_size,
                              hipStream_t stream)
{
    const float* enc    = (const float*)d_in[0];
    const float* esp    = (const float*)d_in[1];
    const float* pre_in = (const float*)d_in[2];
    const float* ah_in  = (const float*)d_in[3];
    const float* h1_in  = (const float*)d_in[4];
    const float* h2_in  = (const float*)d_in[5];
    const float* c1_in  = (const float*)d_in[6];
    const float* c2_in  = (const float*)d_in[7];
    const float* ctx_in = (const float*)d_in[8];
    const float* spk    = (const float*)d_in[9];
    const float* noise  = (const float*)d_in[10];
    const float* cum    = (const float*)d_in[11];
    const float* prv    = (const float*)d_in[12];
    const int*   plen   = (const int*)d_in[13];
    const float* fc1_w  = (const float*)d_in[14];
    const float* fc1_b  = (const float*)d_in[15];
    const float* fc2_w  = (const float*)d_in[16];
    const float* fc2_b  = (const float*)d_in[17];
    const float* conv_w = (const float*)d_in[18];
    const float* L_w    = (const float*)d_in[19];
    const float* L_b    = (const float*)d_in[20];
    const float* W_w    = (const float*)d_in[21];
    const float* W_b    = (const float*)d_in[22];
    const float* v_w    = (const float*)d_in[23];
    const float* g_wih  = (const float*)d_in[24];
    const float* g_whh  = (const float*)d_in[25];
    const float* g_bih  = (const float*)d_in[26];
    const float* g_bhh  = (const float*)d_in[27];
    const float* ri_w   = (const float*)d_in[28];
    const float* ri_b   = (const float*)d_in[29];
    const float* l1_wih = (const float*)d_in[30];
    const float* l1_whh = (const float*)d_in[31];
    const float* l1_bih = (const float*)d_in[32];
    const float* l1_bhh = (const float*)d_in[33];
    const float* l2_wih = (const float*)d_in[34];
    const float* l2_whh = (const float*)d_in[35];
    const float* l2_bih = (const float*)d_in[36];
    const float* l2_bhh = (const float*)d_in[37];
    const float* mel_w  = (const float*)d_in[38];

    int r = (out_size - 808960) / 20480;
    if (r < 1) r = 1;
    if (r > 10) r = 10;

    float* out    = (float*)d_out;
    float* mels   = out;
    float* scores = out + (size_t)20480 * r;
    float* ah_out = scores + 153600;
    float* h1_out = ah_out + 65536;
    float* h2_out = h1_out + 131072;
    float* c1_out = h2_out + 131072;
    float* c2_out = c1_out + 131072;
    float* ctx_out = c2_out + 131072;

    float* ws   = (float*)d_ws;
    float* Xgru = ws;                    // 256*640
    float* Cgi  = Xgru + 163840;         // 256*768
    float* Cgh  = Cgi + 196608;
    float* pq   = Cgh + 196608;          // 256*256
    float* uu   = pq + 65536;            // 256*600
    float* Xrnn = uu + 153600;           // 256*832
    float* x0   = Xrnn + 212992;         // 256*512
    float* x1   = x0 + 131072;
    float* x2   = x1 + 131072;
    float* G    = x2 + 131072;           // 256*2048
    ushort* Lw16 = (ushort*)(G + 524288); // 256*32 bf16 = 16 KB

    prenet_kernel<<<256, 256, 0, stream>>>(pre_in, noise, fc1_w, fc1_b, fc2_w, fc2_b,
                                           ctx_in, spk, L_w, Lw16, Xgru, Xrnn);
    gemm32<<<dim3(8, 12), 256, 0, stream>>>(Xgru, 640, g_wih, nullptr, 0, nullptr, g_bih, Cgi, 768);
    gemm32<<<dim3(8, 12), 256, 0, stream>>>(ah_in, 256, g_whh, nullptr, 0, nullptr, g_bhh, Cgh, 768);
    gru_combine<<<256, 256, 0, stream>>>(Cgi, Cgh, ah_in, ah_out, Xrnn);
    gemm32<<<dim3(8, 4), 256, 0, stream>>>(ah_out, 256, W_w, nullptr, 0, nullptr, W_b, pq, 256);
    attn_u_kernel<<<dim3(10, 256), 256, 0, stream>>>(esp, pq, cum, prv, conv_w, Lw16, L_b, v_w, uu);
    softmax_ctx_kernel<<<256, 1024, 0, stream>>>(uu, plen, enc, scores, ctx_out, Xrnn);
    gemm32<<<dim3(8, 8), 256, 0, stream>>>(Xrnn, 832, ri_w, nullptr, 0, nullptr, ri_b, x0, 512);
    gemm32<<<dim3(8, 32), 256, 0, stream>>>(x0, 512, l1_wih, h1_in, 512, l1_whh, nullptr, G, 2048);
    lstm_combine<<<256, 512, 0, stream>>>(G, l1_bih, l1_bhh, c1_in, x0, h1_out, c1_out, x1);
    gemm32<<<dim3(8, 32), 256, 0, stream>>>(x1, 512, l2_wih, h2_in, 512, l2_whh, nullptr, G, 2048);
    lstm_combine<<<256, 512, 0, stream>>>(G, l2_bih, l2_bhh, c2_in, x1, h2_out, c2_out, x2);
    mel_kernel<<<256, 256, 0, stream>>>(x2, mel_w, r, mels);
}

// Round 9
// 255.736 us; speedup vs baseline: 1.8598x; 1.0300x over previous
//
#include <hip/hip_runtime.h>
#include <hip/hip_bf16.h>
#include <cstdint>

#define B_ 256
#define T_ 600
#define D_ 256

typedef __attribute__((ext_vector_type(8))) short bf16x8;
typedef __attribute__((ext_vector_type(4))) float f32x4;

__device__ __forceinline__ float fast_sigmoid(float x) {
    return __fdividef(1.0f, 1.0f + __expf(-x));
}
__device__ __forceinline__ float fast_tanh(float x) {
    return 1.0f - __fdividef(2.0f, __expf(2.0f * x) + 1.0f);
}
__device__ __forceinline__ ushort f2bf(float f) {
    unsigned u = __float_as_uint(f);
    u += 0x7FFF + ((u >> 16) & 1);   // round-to-nearest-even
    return (ushort)(u >> 16);
}

// ---------------------------------------------------------------------------
// prenet (+ fused init_concat + Lw16 bf16 pre-pack by block 0)
// ---------------------------------------------------------------------------
__global__ __launch_bounds__(256) void prenet_kernel(
    const float* __restrict__ pre_in, const float* __restrict__ noise,
    const float* __restrict__ w1, const float* __restrict__ b1,
    const float* __restrict__ w2, const float* __restrict__ b2,
    const float* __restrict__ ctx_in, const float* __restrict__ spk,
    const float* __restrict__ L_w, ushort* __restrict__ Lw16,
    float* __restrict__ Xgru, float* __restrict__ Xrnn)
{
    __shared__ float xin[144];
    __shared__ float p1[256];
    int b = blockIdx.x, t = threadIdx.x;
    if (b == 0) {
#pragma unroll
        for (int i = 0; i < 32; ++i) {
            int idx = i * 256 + t;
            Lw16[idx] = f2bf(L_w[idx]);
        }
    }
    float s = spk[b * 256 + t];
    Xgru[b * 640 + t] = ctx_in[b * 256 + t];
    Xgru[b * 640 + 384 + t] = s;
    Xrnn[b * 832 + 512 + t] = s;
    if (t < 64) Xrnn[b * 832 + 768 + t] = noise[b * 64 + t];
    if (t < 80) xin[t] = pre_in[b * 80 + t];
    else if (t < 144) xin[t] = noise[b * 64 + (t - 80)];
    __syncthreads();
    float acc = b1[t];
    const float4* w = (const float4*)(w1 + t * 144);
    const float4* xi = (const float4*)xin;
#pragma unroll 9
    for (int k = 0; k < 36; ++k) {
        float4 wv = w[k]; float4 xv = xi[k];
        acc += wv.x * xv.x + wv.y * xv.y + wv.z * xv.z + wv.w * xv.w;
    }
    p1[t] = fmaxf(acc, 0.f);
    __syncthreads();
    if (t < 128) {
        float a2 = b2[t];
        const float4* w2v = (const float4*)(w2 + t * 256);
        const float4* pv = (const float4*)p1;
#pragma unroll 8
        for (int k = 0; k < 64; ++k) {
            float4 wv = w2v[k]; float4 xv = pv[k];
            a2 += wv.x * xv.x + wv.y * xv.y + wv.z * xv.z + wv.w * xv.w;
        }
        Xgru[b * 640 + 256 + t] = fmaxf(a2, 0.f);
    }
}

// ---------------------------------------------------------------------------
// gemm16: C[M,N] = A1[M,K1]@B1^T + A2[M,K2]@B2^T (+bias). 16x64 tile,
// 256 threads, acc 1x4/thread, register-prefetch pipeline. 2x blocks of
// gemm32 -> 2 blocks/CU on the LSTM gemms for latency hiding.
// ---------------------------------------------------------------------------
__global__ __launch_bounds__(256) void gemm16(
    const float* __restrict__ A1, int K1, const float* __restrict__ B1,
    const float* __restrict__ A2, int K2, const float* __restrict__ B2,
    const float* __restrict__ bias, float* __restrict__ C, int N)
{
    __shared__ float As[16][17];
    __shared__ float Bs[16][68];
    int tid = threadIdx.x;
    int m0 = blockIdx.x * 16, n0 = blockIdx.y * 64;
    int tm = tid >> 4, tn = tid & 15;      // out: row tm, cols tn*4..+3
    int lr = tid >> 2, lq = tid & 3;       // B loader: row lr (0..63), quad lq
    int ar = tid >> 2;                     // A loader (tid<64): row 0..15
    float acc[4] = {};
    int nkt = (K1 + K2) >> 4;

    float4 av, bv;
    {
        const float* A; const float* Bb; int kk; int K;
        if (0 < K1) { A = A1; Bb = B1; kk = 0; K = K1; }
        else        { A = A2; Bb = B2; kk = -K1; K = K2; }
        if (tid < 64) av = *(const float4*)&A[(size_t)(m0 + ar) * K + kk + lq * 4];
        bv = *(const float4*)&Bb[(size_t)(n0 + lr) * K + kk + lq * 4];
    }
    for (int kt = 0; kt < nkt; ++kt) {
        __syncthreads();
        if (tid < 64) {
            As[lq * 4 + 0][ar] = av.x; As[lq * 4 + 1][ar] = av.y;
            As[lq * 4 + 2][ar] = av.z; As[lq * 4 + 3][ar] = av.w;
        }
        Bs[lq * 4 + 0][lr] = bv.x; Bs[lq * 4 + 1][lr] = bv.y;
        Bs[lq * 4 + 2][lr] = bv.z; Bs[lq * 4 + 3][lr] = bv.w;
        __syncthreads();
        if (kt + 1 < nkt) {
            int kg = (kt + 1) << 4;
            const float* A; const float* Bb; int kk; int K;
            if (kg < K1) { A = A1; Bb = B1; kk = kg; K = K1; }
            else         { A = A2; Bb = B2; kk = kg - K1; K = K2; }
            if (tid < 64) av = *(const float4*)&A[(size_t)(m0 + ar) * K + kk + lq * 4];
            bv = *(const float4*)&Bb[(size_t)(n0 + lr) * K + kk + lq * 4];
        }
#pragma unroll
        for (int k = 0; k < 16; ++k) {
            float a = As[k][tm];
            float4 b4 = *(const float4*)&Bs[k][tn * 4];
            acc[0] = fmaf(a, b4.x, acc[0]);
            acc[1] = fmaf(a, b4.y, acc[1]);
            acc[2] = fmaf(a, b4.z, acc[2]);
            acc[3] = fmaf(a, b4.w, acc[3]);
        }
    }
    float4 bb = make_float4(0.f, 0.f, 0.f, 0.f);
    if (bias) bb = *(const float4*)&bias[n0 + tn * 4];
    float4 o = make_float4(acc[0] + bb.x, acc[1] + bb.y, acc[2] + bb.z, acc[3] + bb.w);
    *(float4*)&C[(size_t)(m0 + tm) * N + n0 + tn * 4] = o;
}

// ---------------------------------------------------------------------------
// gru_combine
// ---------------------------------------------------------------------------
__global__ __launch_bounds__(256) void gru_combine(
    const float* __restrict__ Cgi, const float* __restrict__ Cgh,
    const float* __restrict__ h_in, float* __restrict__ ah_out,
    float* __restrict__ Xrnn)
{
    int b = blockIdx.x, j = threadIdx.x;
    float gir = Cgi[b * 768 + j], giz = Cgi[b * 768 + 256 + j], gin = Cgi[b * 768 + 512 + j];
    float ghr = Cgh[b * 768 + j], ghz = Cgh[b * 768 + 256 + j], ghn = Cgh[b * 768 + 512 + j];
    float rr = fast_sigmoid(gir + ghr);
    float zz = fast_sigmoid(giz + ghz);
    float nn = fast_tanh(gin + rr * ghn);
    float h = (1.f - zz) * nn + zz * h_in[b * 256 + j];
    ah_out[b * 256 + j] = h;
    Xrnn[b * 832 + 256 + j] = h;
}

// ---------------------------------------------------------------------------
// attn_u v7: L_w fragments in LDS (frees VGPRs), esp float4s preloaded
// BEFORE the first barrier so all 16 are in flight during staging drain.
// grid (10 chunks of 64 t, B), 256 threads = 4 waves x 16 t.
// ---------------------------------------------------------------------------
#define TCH 64
__global__ __launch_bounds__(256) void attn_u_kernel(
    const float* __restrict__ esp, const float* __restrict__ pq,
    const float* __restrict__ cum, const float* __restrict__ prv,
    const float* __restrict__ conv_w, const ushort* __restrict__ Lw16,
    const float* __restrict__ L_b, const float* __restrict__ v_w,
    float* __restrict__ u)
{
    __shared__ float cumL[TCH + 32], prvL[TCH + 32];
    __shared__ float cwL[32 * 62];
    __shared__ ushort lwS[256 * 32];      // bf16 L_w, 16 KB
    __shared__ ushort locs[TCH][32];      // bf16 conv output
    __shared__ float pq2s[256], vvs[256];
    int b = blockIdx.y;
    int t0 = blockIdx.x * TCH;
    int tid = threadIdx.x;
    int lane = tid & 63, wv = tid >> 6;
    int cl = lane & 15, gr = lane >> 4;

    // ---- esp preload: issue all 16 float4 loads up front (drain at barrier)
    int tw = t0 + wv * 16 + cl;
    int tc = (tw < T_) ? tw : (T_ - 1);
    const float4* ep4 = (const float4*)(esp + ((size_t)b * T_ + tc) * 256) + gr;
    float4 ev[16];
#pragma unroll
    for (int dt = 0; dt < 16; ++dt) ev[dt] = ep4[dt * 4];

    // ---- staging
    for (int i = tid; i < TCH + 30; i += 256) {
        int tg = t0 + i - 15;
        bool ok = (tg >= 0) && (tg < T_);
        cumL[i] = ok ? cum[b * T_ + tg] : 0.f;
        prvL[i] = ok ? prv[b * T_ + tg] : 0.f;
    }
    for (int i = tid; i < 32 * 62; i += 256) cwL[i] = conv_w[i];
    {
        const float4* src = (const float4*)Lw16;
        float4* dst = (float4*)lwS;
#pragma unroll
        for (int i = 0; i < 4; ++i) dst[tid + i * 256] = src[tid + i * 256];
    }
    pq2s[tid] = pq[b * 256 + tid] + L_b[tid];
    vvs[tid] = v_w[tid];
    __syncthreads();

    // ---- conv (LDS stencil)
    {
        int f = tid & 31, ts = tid >> 5;
        const float* c0 = &cwL[f * 62];
        float acc[8] = {};
#pragma unroll
        for (int k = 0; k < 31; ++k) {
            float wcv = c0[k], wpv = c0[31 + k];
#pragma unroll
            for (int i = 0; i < 8; ++i)
                acc[i] = fmaf(cumL[ts * 8 + i + k], wcv, fmaf(prvL[ts * 8 + i + k], wpv, acc[i]));
        }
#pragma unroll
        for (int i = 0; i < 8; ++i)
            locs[ts * 8 + i][f] = f2bf(acc[i]);
    }
    __syncthreads();

    // ---- MFMA + tanh, all operands in regs/LDS
    bf16x8 locf = *(const bf16x8*)&locs[wv * 16 + cl][gr * 8];
    float sum = 0.f;
#pragma unroll
    for (int dt = 0; dt < 16; ++dt) {
        bf16x8 af = *(const bf16x8*)&lwS[(dt * 16 + cl) * 32 + gr * 8];
        float4 pq4 = *(const float4*)&pq2s[dt * 16 + gr * 4];
        float4 vv4 = *(const float4*)&vvs[dt * 16 + gr * 4];
        f32x4 acc = {pq4.x, pq4.y, pq4.z, pq4.w};
        acc = __builtin_amdgcn_mfma_f32_16x16x32_bf16(af, locf, acc, 0, 0, 0);
        sum = fmaf(fast_tanh(ev[dt].x + acc[0]), vv4.x, sum);
        sum = fmaf(fast_tanh(ev[dt].y + acc[1]), vv4.y, sum);
        sum = fmaf(fast_tanh(ev[dt].z + acc[2]), vv4.z, sum);
        sum = fmaf(fast_tanh(ev[dt].w + acc[3]), vv4.w, sum);
    }
    sum += __shfl_xor(sum, 16, 64);
    sum += __shfl_xor(sum, 32, 64);
    if (lane < 16 && tw < T_) u[b * T_ + tw] = sum;
}

// ---------------------------------------------------------------------------
// softmax + context (1024 threads; context loop 2-way unrolled)
// ---------------------------------------------------------------------------
__global__ __launch_bounds__(1024) void softmax_ctx_kernel(
    const float* __restrict__ u, const int* __restrict__ plen,
    const float* __restrict__ enc,
    float* __restrict__ scores, float* __restrict__ ctx_out,
    float* __restrict__ Xrnn)
{
    __shared__ float sc[T_];
    __shared__ float red[16];
    __shared__ float part[16][256];
    int b = blockIdx.x, tid = threadIdx.x;
    int lane = tid & 63, wid = tid >> 6;
    int pl = plen[b];
    float mv = -1e30f;
    if (tid < T_) {
        float uv = u[b * T_ + tid];
        mv = (tid < pl) ? uv : -1e9f;
        sc[tid] = mv;
    }
    float m = mv;
#pragma unroll
    for (int off = 32; off > 0; off >>= 1) m = fmaxf(m, __shfl_xor(m, off, 64));
    if (lane == 0) red[wid] = m;
    __syncthreads();
    m = red[0];
#pragma unroll
    for (int i = 1; i < 16; ++i) m = fmaxf(m, red[i]);
    float ev = 0.f;
    if (tid < T_) ev = __expf(sc[tid] - m);
    float s = ev;
    __syncthreads();
#pragma unroll
    for (int off = 32; off > 0; off >>= 1) s += __shfl_xor(s, off, 64);
    if (lane == 0) red[wid] = s;
    __syncthreads();
    float tot = 0.f;
#pragma unroll
    for (int i = 0; i < 16; ++i) tot += red[i];
    float inv = __fdividef(1.0f, tot);
    if (tid < T_) {
        float scv = ev * inv;
        scores[b * T_ + tid] = scv;
        sc[tid] = scv;
    }
    __syncthreads();
    // context: wave wid owns t = wid + 32k and t = wid+16 + 32k (2 chains)
    float a0 = 0.f, a1 = 0.f, a2 = 0.f, a3 = 0.f;
    float c0 = 0.f, c1 = 0.f, c2 = 0.f, c3 = 0.f;
    const float4* epA = (const float4*)(enc + ((size_t)b * T_ + wid) * 256) + lane;
    const float4* epB = epA + 16 * 64;
    for (int t = wid; t + 16 < T_; t += 32) {
        float svA = sc[t];
        float svB = sc[t + 16];
        float4 eA = *epA;
        float4 eB = *epB;
        a0 = fmaf(svA, eA.x, a0); a1 = fmaf(svA, eA.y, a1);
        a2 = fmaf(svA, eA.z, a2); a3 = fmaf(svA, eA.w, a3);
        c0 = fmaf(svB, eB.x, c0); c1 = fmaf(svB, eB.y, c1);
        c2 = fmaf(svB, eB.z, c2); c3 = fmaf(svB, eB.w, c3);
        epA += 32 * 64;
        epB += 32 * 64;
    }
    // tail: T_=600 -> t=wid+576 (wid<24) handled when wid+576 < 600 and pair missing
    {
        int t = (T_ / 32) * 32 + wid;       // 576 + wid
        if (t < T_ && ((t - wid) & 31) == 0 && (t & 31) == wid && false) {}
        // handled below generically
    }
    // generic tail for remaining t >= last full pair
    for (int t = wid + ((600 - wid - 1) / 32) * 32 + 32 - 32; false;) {}
    // (T_=600: wid in [0,16) covers t=wid..wid+584 step 32 pairs; last pair t=wid+576,
    //  t+16=wid+592 <= 599 iff wid<8. Handle odd leftover:)
    if (wid >= 8) {
        int t = 592 + (wid - 8);
        if (t < T_) {
            float sv = sc[t];
            const float4* ep = (const float4*)(enc + ((size_t)b * T_ + t) * 256) + lane;
            float4 e4 = *ep;
            a0 = fmaf(sv, e4.x, a0); a1 = fmaf(sv, e4.y, a1);
            a2 = fmaf(sv, e4.z, a2); a3 = fmaf(sv, e4.w, a3);
        }
    }
    a0 += c0; a1 += c1; a2 += c2; a3 += c3;
    part[wid][lane * 4 + 0] = a0;
    part[wid][lane * 4 + 1] = a1;
    part[wid][lane * 4 + 2] = a2;
    part[wid][lane * 4 + 3] = a3;
    __syncthreads();
    if (tid < 256) {
        float c = 0.f;
#pragma unroll
        for (int q = 0; q < 16; ++q) c += part[q][tid];
        ctx_out[b * 256 + tid] = c;
        Xrnn[b * 832 + tid] = c;
    }
}

// ---------------------------------------------------------------------------
// lstm_combine
// ---------------------------------------------------------------------------
__global__ __launch_bounds__(512) void lstm_combine(
    const float* __restrict__ G, const float* __restrict__ bih,
    const float* __restrict__ bhh, const float* __restrict__ c_in,
    const float* __restrict__ x_in, float* __restrict__ h_out,
    float* __restrict__ c_out, float* __restrict__ x_next)
{
    int b = blockIdx.x, j = threadIdx.x;
    size_t base = (size_t)b * 2048;
    float gi = G[base + j] + bih[j] + bhh[j];
    float gf = G[base + 512 + j] + bih[512 + j] + bhh[512 + j];
    float gg = G[base + 1024 + j] + bih[1024 + j] + bhh[1024 + j];
    float go = G[base + 1536 + j] + bih[1536 + j] + bhh[1536 + j];
    float c = fast_sigmoid(gf) * c_in[b * 512 + j] + fast_sigmoid(gi) * fast_tanh(gg);
    float h = fast_sigmoid(go) * fast_tanh(c);
    h_out[b * 512 + j] = h;
    c_out[b * 512 + j] = c;
    x_next[b * 512 + j] = x_in[b * 512 + j] + h;
}

// ---------------------------------------------------------------------------
// mel
// ---------------------------------------------------------------------------
__global__ __launch_bounds__(256) void mel_kernel(
    const float* __restrict__ x2, const float* __restrict__ mel_w,
    int r, float* __restrict__ mels)
{
    __shared__ float xl[512];
    int b = blockIdx.x, tid = threadIdx.x;
    xl[tid] = x2[b * 512 + tid];
    xl[256 + tid] = x2[b * 512 + 256 + tid];
    __syncthreads();
    for (int idx = tid; idx < 80 * r; idx += 256) {
        int mrow = (idx / r) * 10 + (idx % r);
        const float4* w = (const float4*)(mel_w + (size_t)mrow * 512);
        const float4* xv = (const float4*)xl;
        float acc = 0.f;
#pragma unroll 16
        for (int k = 0; k < 128; ++k) {
            float4 a = w[k], c = xv[k];
            acc += a.x * c.x + a.y * c.y + a.z * c.z + a.w * c.w;
        }
        mels[(size_t)b * 80 * r + idx] = acc;
    }
}

// ---------------------------------------------------------------------------
extern "C" void kernel_launch(void* const* d_in, const int* in_sizes, int n_in,
                              void* d_out, int out_size, void* d_ws, size_t ws_size,
                              hipStream_t stream)
{
    const float* enc    = (const float*)d_in[0];
    const float* esp    = (const float*)d_in[1];
    const float* pre_in = (const float*)d_in[2];
    const float* ah_in  = (const float*)d_in[3];
    const float* h1_in  = (const float*)d_in[4];
    const float* h2_in  = (const float*)d_in[5];
    const float* c1_in  = (const float*)d_in[6];
    const float* c2_in  = (const float*)d_in[7];
    const float* ctx_in = (const float*)d_in[8];
    const float* spk    = (const float*)d_in[9];
    const float* noise  = (const float*)d_in[10];
    const float* cum    = (const float*)d_in[11];
    const float* prv    = (const float*)d_in[12];
    const int*   plen   = (const int*)d_in[13];
    const float* fc1_w  = (const float*)d_in[14];
    const float* fc1_b  = (const float*)d_in[15];
    const float* fc2_w  = (const float*)d_in[16];
    const float* fc2_b  = (const float*)d_in[17];
    const float* conv_w = (const float*)d_in[18];
    const float* L_w    = (const float*)d_in[19];
    const float* L_b    = (const float*)d_in[20];
    const float* W_w    = (const float*)d_in[21];
    const float* W_b    = (const float*)d_in[22];
    const float* v_w    = (const float*)d_in[23];
    const float* g_wih  = (const float*)d_in[24];
    const float* g_whh  = (const float*)d_in[25];
    const float* g_bih  = (const float*)d_in[26];
    const float* g_bhh  = (const float*)d_in[27];
    const float* ri_w   = (const float*)d_in[28];
    const float* ri_b   = (const float*)d_in[29];
    const float* l1_wih = (const float*)d_in[30];
    const float* l1_whh = (const float*)d_in[31];
    const float* l1_bih = (const float*)d_in[32];
    const float* l1_bhh = (const float*)d_in[33];
    const float* l2_wih = (const float*)d_in[34];
    const float* l2_whh = (const float*)d_in[35];
    const float* l2_bih = (const float*)d_in[36];
    const float* l2_bhh = (const float*)d_in[37];
    const float* mel_w  = (const float*)d_in[38];

    int r = (out_size - 808960) / 20480;
    if (r < 1) r = 1;
    if (r > 10) r = 10;

    float* out    = (float*)d_out;
    float* mels   = out;
    float* scores = out + (size_t)20480 * r;
    float* ah_out = scores + 153600;
    float* h1_out = ah_out + 65536;
    float* h2_out = h1_out + 131072;
    float* c1_out = h2_out + 131072;
    float* c2_out = c1_out + 131072;
    float* ctx_out = c2_out + 131072;

    float* ws   = (float*)d_ws;
    float* Xgru = ws;                    // 256*640
    float* Cgi  = Xgru + 163840;         // 256*768
    float* Cgh  = Cgi + 196608;
    float* pq   = Cgh + 196608;          // 256*256
    float* uu   = pq + 65536;            // 256*600
    float* Xrnn = uu + 153600;           // 256*832
    float* x0   = Xrnn + 212992;         // 256*512
    float* x1   = x0 + 131072;
    float* x2   = x1 + 131072;
    float* G    = x2 + 131072;           // 256*2048
    ushort* Lw16 = (ushort*)(G + 524288); // 256*32 bf16 = 16 KB

    prenet_kernel<<<256, 256, 0, stream>>>(pre_in, noise, fc1_w, fc1_b, fc2_w, fc2_b,
                                           ctx_in, spk, L_w, Lw16, Xgru, Xrnn);
    gemm16<<<dim3(16, 12), 256, 0, stream>>>(Xgru, 640, g_wih, nullptr, 0, nullptr, g_bih, Cgi, 768);
    gemm16<<<dim3(16, 12), 256, 0, stream>>>(ah_in, 256, g_whh, nullptr, 0, nullptr, g_bhh, Cgh, 768);
    gru_combine<<<256, 256, 0, stream>>>(Cgi, Cgh, ah_in, ah_out, Xrnn);
    gemm16<<<dim3(16, 4), 256, 0, stream>>>(ah_out, 256, W_w, nullptr, 0, nullptr, W_b, pq, 256);
    attn_u_kernel<<<dim3(10, 256), 256, 0, stream>>>(esp, pq, cum, prv, conv_w, Lw16, L_b, v_w, uu);
    softmax_ctx_kernel<<<256, 1024, 0, stream>>>(uu, plen, enc, scores, ctx_out, Xrnn);
    gemm16<<<dim3(16, 8), 256, 0, stream>>>(Xrnn, 832, ri_w, nullptr, 0, nullptr, ri_b, x0, 512);
    gemm16<<<dim3(16, 32), 256, 0, stream>>>(x0, 512, l1_wih, h1_in, 512, l1_whh, nullptr, G, 2048);
    lstm_combine<<<256, 512, 0, stream>>>(G, l1_bih, l1_bhh, c1_in, x0, h1_out, c1_out, x1);
    gemm16<<<dim3(16, 32), 256, 0, stream>>>(x1, 512, l2_wih, h2_in, 512, l2_whh, nullptr, G, 2048);
    lstm_combine<<<256, 512, 0, stream>>>(G, l2_bih, l2_bhh, c2_in, x1, h2_out, c2_out, x2);
    mel_kernel<<<256, 256, 0, stream>>>(x2, mel_w, r, mels);
}